// Round 6
// baseline (4250.068 us; speedup 1.0000x reference)
//
#include <hip/hip_runtime.h>

#define NN 50000
#define IN_DIM 128
#define HD 96
#define BN_EPS 1e-5f
#define PN_SCALE 20.0f
#define SCAN_NB 196   // ceil(50000/256)

__device__ __forceinline__ float4 ld4(const float* p) { return *(const float4*)p; }
__device__ __forceinline__ float4 add4(float4 a, float4 b) {
    return make_float4(a.x + b.x, a.y + b.y, a.z + b.z, a.w + b.w);
}

// ---------------- zero stats + CSR counters ----------------
__global__ void zero_kernel(float* stats, int* cnt) {
    int i = blockIdx.x * blockDim.x + threadIdx.x;
    if (i < 1024) stats[i] = 0.0f;
    int j = i - 1024;
    if (j >= 0 && j < NN) cnt[j] = 0;
}

// ---------------- register-streaming GEMM: C[N,96] = act(A[N,K]) @ W[96,K]^T + b
// Single-wave blocks (64 threads, 64 rows). Lane tile [4 rows][24 cols].
// W k-chunk [32][96] lives in wave-private LDS (12.3 KB) -> NO barriers at all;
// DS in-order per wave replaces __syncthreads. A streams global->reg, one 4-kk
// group prefetched ahead (ping-pong pa/pb). W next chunk prefetched in regs.
// Per kk: 6 ds_read_b128 (16-lane broadcast, conflict-free) + 96 FMA ->
// LDS port ~72cyc vs CU-VALU 48cyc (was 42 vs 12: 3.5x LDS-bound + barriers).
// MODE 0: fused edge histogram, 4 atomics/chunk so they drain under compute.
// Epilogue stats via __shfl_xor butterflies (no LDS, no barrier).
template<int K, int MODE>
__global__ __launch_bounds__(64) void gemm_rs(
    const float* __restrict__ A, const float* __restrict__ W, const float* __restrict__ bias,
    float* __restrict__ out, const float* __restrict__ scale, const float* __restrict__ shift,
    float* __restrict__ gsum, float* __restrict__ gsumsq,
    float* __restrict__ gcol, float* __restrict__ growss,
    const int* __restrict__ ei, int* __restrict__ hist_cnt, int E)
{
    constexpr int NC = K / 32;
    __shared__ float Ws[32 * 96];          // k-major W chunk [kk][col]
    const int l  = threadIdx.x;            // 0..63
    const int cg = l & 3;                  // cols cg*24 .. +23
    const int tr = l >> 2;                 // 0..15
    const int base = blockIdx.x * 64;

    int row[4]; bool rok[4];
#pragma unroll
    for (int i = 0; i < 4; ++i) { row[i] = base + tr + i * 16; rok[i] = row[i] < NN; }

    float acc[4][24];
#pragma unroll
    for (int i = 0; i < 4; ++i)
#pragma unroll
        for (int j = 0; j < 24; ++j) acc[i][j] = 0.0f;

    float4 ws[12];
    auto load_ws = [&](int kc) {           // stage W chunk into regs (12 b128)
#pragma unroll
        for (int s = 0; s < 12; ++s) {
            int u = l + 64 * s;
            int col = u % 96, kq = u / 96;
            ws[s] = ld4(W + (size_t)col * K + kc + kq * 4);
        }
    };
    auto write_ws = [&]() {                // regs -> LDS (transposed, 2-way banks)
#pragma unroll
        for (int s = 0; s < 12; ++s) {
            int u = l + 64 * s;
            int col = u % 96, kq = u / 96;
            float* d = Ws + kq * 4 * 96 + col;
            d[0]     = ws[s].x;
            d[96]    = ws[s].y;
            d[192]   = ws[s].z;
            d[288]   = ws[s].w;
        }
    };
    auto load_a = [&](int kc4, float4* pa) {
#pragma unroll
        for (int i = 0; i < 4; ++i)
            pa[i] = rok[i] ? ld4(A + (size_t)row[i] * K + kc4)
                           : make_float4(0.f, 0.f, 0.f, 0.f);
    };
    auto compute_g = [&](int kc4, float4* pa) {   // one 4-kk group
        float av[4][4];
        if (MODE == 2) {
            float4 sc = ld4(scale + kc4), sh = ld4(shift + kc4);
#pragma unroll
            for (int i = 0; i < 4; ++i) {
                av[i][0] = fmaxf(pa[i].x * sc.x + sh.x, 0.f);
                av[i][1] = fmaxf(pa[i].y * sc.y + sh.y, 0.f);
                av[i][2] = fmaxf(pa[i].z * sc.z + sh.z, 0.f);
                av[i][3] = fmaxf(pa[i].w * sc.w + sh.w, 0.f);
            }
        } else {
#pragma unroll
            for (int i = 0; i < 4; ++i) {
                av[i][0] = pa[i].x; av[i][1] = pa[i].y;
                av[i][2] = pa[i].z; av[i][3] = pa[i].w;
            }
        }
        const int kk0 = kc4 & 31;
#pragma unroll
        for (int q = 0; q < 4; ++q) {
            float w[24];
#pragma unroll
            for (int m = 0; m < 6; ++m) {
                float4 wv = *(const float4*)(Ws + (kk0 + q) * 96 + cg * 24 + m * 4);
                w[m*4+0] = wv.x; w[m*4+1] = wv.y; w[m*4+2] = wv.z; w[m*4+3] = wv.w;
            }
#pragma unroll
            for (int i = 0; i < 4; ++i) {
                float a = av[i][q];
#pragma unroll
                for (int j = 0; j < 24; ++j) acc[i][j] = fmaf(a, w[j], acc[i][j]);
            }
        }
    };

    load_ws(0);
#pragma unroll
    for (int c = 0; c < NC; ++c) {
        const int kc = c * 32;
        write_ws();                          // LDS <- chunk c (vmcnt waits on ws)
        if (c + 1 < NC) load_ws(kc + 32);    // prefetch chunk c+1 into regs
        if (MODE == 0) {                     // 4 hist atomics per chunk
            int e0 = (blockIdx.x * 64 + l) * (NC * 4) + c * 4;
            if (e0 + 4 <= E) {
                int4 d4 = *(const int4*)(ei + E + e0);
                atomicAdd(&hist_cnt[d4.x], 1); atomicAdd(&hist_cnt[d4.y], 1);
                atomicAdd(&hist_cnt[d4.z], 1); atomicAdd(&hist_cnt[d4.w], 1);
            } else {
#pragma unroll
                for (int i = 0; i < 4; ++i) {
                    int e = e0 + i;
                    if (e < E) atomicAdd(&hist_cnt[ei[E + e]], 1);
                }
            }
        }
        float4 pa[4], pb[4];
        load_a(kc, pa);
#pragma unroll
        for (int h = 0; h < 4; ++h) {
            load_a(kc + h * 8 + 4, pb);      // prefetch odd group
            compute_g(kc + h * 8, pa);
            if (h < 3) load_a(kc + h * 8 + 8, pa);   // prefetch next even group
            compute_g(kc + h * 8 + 4, pb);
        }
    }

    // ---- epilogue: bias, store, fused stats (shfl butterflies, no LDS) ----
    {
        float bv[24];
#pragma unroll
        for (int m = 0; m < 6; ++m) {
            float4 b4 = ld4(bias + cg * 24 + m * 4);
            bv[m*4+0] = b4.x; bv[m*4+1] = b4.y; bv[m*4+2] = b4.z; bv[m*4+3] = b4.w;
        }
#pragma unroll
        for (int i = 0; i < 4; ++i)
#pragma unroll
            for (int j = 0; j < 24; ++j) acc[i][j] += bv[j];
    }
#pragma unroll
    for (int i = 0; i < 4; ++i) {
        if (rok[i]) {
            float* o = out + (size_t)row[i] * HD + cg * 24;
#pragma unroll
            for (int m = 0; m < 6; ++m)
                *(float4*)(o + m * 4) = make_float4(acc[i][m*4+0], acc[i][m*4+1],
                                                    acc[i][m*4+2], acc[i][m*4+3]);
        }
    }

    if (MODE == 1) {
        float s[24], q[24];
#pragma unroll
        for (int j = 0; j < 24; ++j) {
            float ss = 0.f, qq = 0.f;
#pragma unroll
            for (int i = 0; i < 4; ++i) {
                float v = rok[i] ? acc[i][j] : 0.f;
                ss += v; qq += v * v;
            }
            s[j] = ss; q[j] = qq;
        }
#pragma unroll
        for (int d = 4; d <= 32; d <<= 1)
#pragma unroll
            for (int j = 0; j < 24; ++j) {
                s[j] += __shfl_xor(s[j], d);
                q[j] += __shfl_xor(q[j], d);
            }
        // 48 items over 16 tr-lanes, 3 each; static indices only
#pragma unroll
        for (int it = 0; it < 48; ++it) {
            if (tr == it / 3) {
                if (it < 24) atomicAdd(&gsum[cg * 24 + it], s[it]);
                else         atomicAdd(&gsumsq[cg * 24 + (it - 24)], q[it - 24]);
            }
        }
    }

    if (MODE == 2) {
        float s[24];
#pragma unroll
        for (int j = 0; j < 24; ++j) {
            float ss = 0.f;
#pragma unroll
            for (int i = 0; i < 4; ++i) ss += rok[i] ? acc[i][j] : 0.f;
            s[j] = ss;
        }
#pragma unroll
        for (int d = 4; d <= 32; d <<= 1)
#pragma unroll
            for (int j = 0; j < 24; ++j) s[j] += __shfl_xor(s[j], d);
#pragma unroll
        for (int it = 0; it < 24; ++it) {
            int owner = (it < 16) ? (it >> 1) : (it - 8);
            if (tr == owner) atomicAdd(&gcol[cg * 24 + it], s[it]);
        }
        float rq[4];
#pragma unroll
        for (int i = 0; i < 4; ++i) {
            float qq = 0.f;
#pragma unroll
            for (int j = 0; j < 24; ++j) qq += acc[i][j] * acc[i][j];
            qq += __shfl_xor(qq, 1);
            qq += __shfl_xor(qq, 2);
            rq[i] = qq;
        }
        if (cg == 0) {
#pragma unroll
            for (int i = 0; i < 4; ++i)
                if (rok[i]) growss[row[i]] = rq[i];
        }
    }
}

// ---------------- CSR build ----------------
__global__ __launch_bounds__(256) void scan_part1(const int* __restrict__ cnt,
                                                  int* __restrict__ bsum) {
    __shared__ int sh[256];
    int i = blockIdx.x * 256 + threadIdx.x;
    int t = threadIdx.x;
    sh[t] = (i < NN) ? cnt[i] : 0;
    __syncthreads();
    for (int off = 128; off > 0; off >>= 1) {
        if (t < off) sh[t] += sh[t + off];
        __syncthreads();
    }
    if (t == 0) bsum[blockIdx.x] = sh[0];
}

__global__ __launch_bounds__(256) void scan_part2(int* __restrict__ bsum) {
    __shared__ int sh[256];
    int t = threadIdx.x;
    int v = (t < SCAN_NB) ? bsum[t] : 0;
    sh[t] = v;
    __syncthreads();
    for (int off = 1; off < 256; off <<= 1) {
        int u = sh[t];
        if (t >= off) u += sh[t - off];
        __syncthreads();
        sh[t] = u;
        __syncthreads();
    }
    if (t < SCAN_NB) bsum[t] = sh[t] - v;    // exclusive block offsets
}

__global__ __launch_bounds__(256) void scan_part3(int* __restrict__ cnt,
                                                  const int* __restrict__ bsum,
                                                  int* __restrict__ rowptr) {
    __shared__ int sh[256];
    int i = blockIdx.x * 256 + threadIdx.x;
    int t = threadIdx.x;
    int v = (i < NN) ? cnt[i] : 0;
    sh[t] = v;
    __syncthreads();
    for (int off = 1; off < 256; off <<= 1) {
        int u = sh[t];
        if (t >= off) u += sh[t - off];
        __syncthreads();
        sh[t] = u;
        __syncthreads();
    }
    int excl = sh[t] - v + bsum[blockIdx.x];
    if (i < NN) { rowptr[i] = excl; cnt[i] = excl; }   // cnt becomes fill cursor
    if (i == NN - 1) rowptr[NN] = excl + v;
}

// fill with dst-range multipass: clusters slot-writes of a row in time so the
// srcs write window per pass (~460 KB) stays L2-resident -> line coalescing.
// (Round-1 A/B: removing the pass clustering raised WRITE_SIZE 40->52.6 MB and
// slowed fill 46.5->55 us despite 2x occupancy -> clustering is load-bearing.)
__global__ __launch_bounds__(256) void fill_kernel(const int* __restrict__ ei,
                                                   int* __restrict__ cursor,
                                                   int* __restrict__ srcs, int E) {
    int t2 = blockIdx.x * 256 + threadIdx.x;
    int e0 = t2 * 2;
    int src[2], dst[2];
#pragma unroll
    for (int i = 0; i < 2; ++i) {
        int e = e0 + i;
        bool ok = e < E;
        dst[i] = ok ? ei[E + e] : -1;
        src[i] = ok ? ei[e] : 0;
    }
    for (int pass = 0; pass < 7; ++pass) {
#pragma unroll
        for (int i = 0; i < 2; ++i) {
            if (dst[i] >= 0 && (dst[i] >> 13) == pass) {
                int slot = atomicAdd(&cursor[dst[i]], 1);
                srcs[slot] = src[i];
            }
        }
    }
}

// -------- gather: z[i] = h0[i] + sum_{e:dst=i} h0[src_e] --------------------
// One 24-lane group owns a full row (24 x float4 = 96 floats). No LDS, no
// __syncthreads: waves retire independently, 8-deep load batches give MLP.
__global__ __launch_bounds__(192) void gather_kernel(
    const float* __restrict__ h0, const int* __restrict__ rowptr,
    const int* __restrict__ srcs, float* __restrict__ z)
{
    const int tid = threadIdx.x;
    const int rl  = tid / 24;          // 0..7 local row
    const int c   = tid - rl * 24;     // 0..23 float4 lane
    const int row = blockIdx.x * 8 + rl;
    if (row >= NN) return;

    const int p0 = rowptr[row];
    const int p1 = rowptr[row + 1];

    float4 acc = ld4(h0 + (size_t)row * HD + c * 4);

    int p = p0;
    for (; p + 8 <= p1; p += 8) {
        int s0 = srcs[p + 0], s1 = srcs[p + 1], s2 = srcs[p + 2], s3 = srcs[p + 3];
        int s4 = srcs[p + 4], s5 = srcs[p + 5], s6 = srcs[p + 6], s7 = srcs[p + 7];
        float4 v0 = ld4(h0 + (size_t)s0 * HD + c * 4);
        float4 v1 = ld4(h0 + (size_t)s1 * HD + c * 4);
        float4 v2 = ld4(h0 + (size_t)s2 * HD + c * 4);
        float4 v3 = ld4(h0 + (size_t)s3 * HD + c * 4);
        float4 v4 = ld4(h0 + (size_t)s4 * HD + c * 4);
        float4 v5 = ld4(h0 + (size_t)s5 * HD + c * 4);
        float4 v6 = ld4(h0 + (size_t)s6 * HD + c * 4);
        float4 v7 = ld4(h0 + (size_t)s7 * HD + c * 4);
        acc = add4(acc, add4(add4(add4(v0, v1), add4(v2, v3)),
                             add4(add4(v4, v5), add4(v6, v7))));
    }
    for (; p + 4 <= p1; p += 4) {
        int s0 = srcs[p + 0], s1 = srcs[p + 1], s2 = srcs[p + 2], s3 = srcs[p + 3];
        float4 v0 = ld4(h0 + (size_t)s0 * HD + c * 4);
        float4 v1 = ld4(h0 + (size_t)s1 * HD + c * 4);
        float4 v2 = ld4(h0 + (size_t)s2 * HD + c * 4);
        float4 v3 = ld4(h0 + (size_t)s3 * HD + c * 4);
        acc = add4(acc, add4(add4(v0, v1), add4(v2, v3)));
    }
    for (; p < p1; ++p)
        acc = add4(acc, ld4(h0 + (size_t)srcs[p] * HD + c * 4));

    *(float4*)(z + (size_t)row * HD + c * 4) = acc;
}

__global__ void bn_finalize_kernel(const float* __restrict__ sum, const float* __restrict__ sumsq,
                                   const float* __restrict__ gamma, const float* __restrict__ beta,
                                   float* __restrict__ scale, float* __restrict__ shift)
{
    int f = threadIdx.x;
    if (f < HD) {
        float mean = sum[f] * (1.0f / NN);
        float var  = fmaxf(sumsq[f] * (1.0f / NN) - mean * mean, 0.0f);
        float rstd = rsqrtf(var + BN_EPS);
        float sc = rstd * gamma[f];
        scale[f] = sc;
        shift[f] = beta[f] - mean * sc;
    }
}

// ---------------- PairNorm: streaming float4, in place ----------------
__global__ __launch_bounds__(256) void pn_kernel(float* l1, const float* __restrict__ colsum,
                                                 const float* __restrict__ rowss)
{
    int idx = blockIdx.x * 256 + threadIdx.x;   // float4 index
    if (idx >= NN * 24) return;
    int row = idx / 24;
    int q = idx - row * 24;
    float rs = rsqrtf(1e-6f + rowss[row]);
    float4 v = ld4(l1 + (size_t)idx * 4);
    float4 cm = ld4(colsum + q * 4);
    v.x = PN_SCALE * v.x * rs - cm.x * (1.0f / NN);
    v.y = PN_SCALE * v.y * rs - cm.y * (1.0f / NN);
    v.z = PN_SCALE * v.z * rs - cm.z * (1.0f / NN);
    v.w = PN_SCALE * v.w * rs - cm.w * (1.0f / NN);
    *(float4*)(l1 + (size_t)idx * 4) = v;
}

extern "C" void kernel_launch(void* const* d_in, const int* in_sizes, int n_in,
                              void* d_out, int out_size, void* d_ws, size_t ws_size,
                              hipStream_t stream) {
    const float* x     = (const float*)d_in[0];
    const int*   ei    = (const int*)d_in[1];
    const float* W0    = (const float*)d_in[2];
    const float* b0    = (const float*)d_in[3];
    const float* W1    = (const float*)d_in[4];
    const float* b1    = (const float*)d_in[5];
    const float* gamma = (const float*)d_in[6];
    const float* beta  = (const float*)d_in[7];
    const float* W2    = (const float*)d_in[8];
    const float* b2    = (const float*)d_in[9];

    float* out_l1 = (float*)d_out;                 // [N,96]: z -> h -> l1 (in place)
    float* out_h0 = out_l1 + (size_t)NN * HD;      // [N,96]: h0 output

    float* stats   = (float*)d_ws;
    float* s_sum   = stats;            // 96
    float* s_sumsq = stats + HD;       // 96
    float* s_col   = stats + 2 * HD;   // 96
    float* s_scale = stats + 288;      // 96
    float* s_shift = stats + 384;      // 96
    float* rowss = stats + 1024;
    int* cnt    = (int*)(rowss + NN);
    int* rowptr = cnt + NN;
    int* bsum   = rowptr + NN + 2;
    int* srcs   = bsum + 256;

    const int E = in_sizes[1] / 2;                 // 800000
    const int GB = (NN + 63) / 64;                 // 782

    zero_kernel<<<(1024 + NN + 255) / 256, 256, 0, stream>>>(stats, cnt);
    // 1) h0 = x @ W0^T + b0, edge histogram fused (4 atomics/chunk under compute)
    gemm_rs<IN_DIM, 0><<<GB, 64, 0, stream>>>(x, W0, b0, out_h0, nullptr, nullptr,
                                              nullptr, nullptr, nullptr, nullptr,
                                              ei, cnt, E);
    // 2) CSR build: hierarchical scan -> multipass fill
    scan_part1<<<SCAN_NB, 256, 0, stream>>>(cnt, bsum);
    scan_part2<<<1, 256, 0, stream>>>(bsum);
    scan_part3<<<SCAN_NB, 256, 0, stream>>>(cnt, bsum, rowptr);
    fill_kernel<<<(E / 2 + 255) / 256, 256, 0, stream>>>(ei, cnt, srcs, E);
    // 3) gather: z = h0 + segment_sum(h0[src])
    gather_kernel<<<(NN + 7) / 8, 192, 0, stream>>>(out_h0, rowptr, srcs, out_l1);
    // 4) h = z @ W1^T + b1 (in place) + fused BN stats
    gemm_rs<HD, 1><<<GB, 64, 0, stream>>>(out_l1, W1, b1, out_l1, nullptr, nullptr,
                                          s_sum, s_sumsq, nullptr, nullptr,
                                          nullptr, nullptr, 0);
    bn_finalize_kernel<<<1, 128, 0, stream>>>(s_sum, s_sumsq, gamma, beta, s_scale, s_shift);
    // 5) l1 = relu(bn(h)) @ W2^T + b2 (in place) + fused PN stats
    gemm_rs<HD, 2><<<GB, 64, 0, stream>>>(out_l1, W2, b2, out_l1, s_scale, s_shift,
                                          nullptr, nullptr, s_col, rowss,
                                          nullptr, nullptr, 0);
    // 6) PairNorm finalize (streaming, in place)
    pn_kernel<<<(NN * 24 + 255) / 256, 256, 0, stream>>>(out_l1, s_col, rowss);
}

// Round 8
// 940.504 us; speedup vs baseline: 4.5189x; 4.5189x over previous
//
#include <hip/hip_runtime.h>

#define NN 50000
#define IN_DIM 128
#define HD 96
#define BN_EPS 1e-5f
#define PN_SCALE 20.0f
#define SCAN_NB 196   // ceil(50000/256)

__device__ __forceinline__ float4 ld4(const float* p) { return *(const float4*)p; }
__device__ __forceinline__ float4 add4(float4 a, float4 b) {
    return make_float4(a.x + b.x, a.y + b.y, a.z + b.z, a.w + b.w);
}

// ---------------- zero stats + CSR counters ----------------
__global__ void zero_kernel(float* stats, int* cnt) {
    int i = blockIdx.x * blockDim.x + threadIdx.x;
    if (i < 1024) stats[i] = 0.0f;
    int j = i - 1024;
    if (j >= 0 && j < NN) cnt[j] = 0;
}

// ---- scalar-W GEMM: C[N,96] = act(A[N,K]) @ W[96,K]^T + b ------------------
// 512-thread blocks = 8 waves; wave w owns cols 12w..12w+11 for the block's
// 64 rows; lane = row. W fragment is wave-uniform (readfirstlane col base) ->
// scalar loads, SGPR operand FMAs. acc[12] + A ping-pong ~= 60 VGPR, no spill
// (round-6 lesson: 256-VGPR spill = 987MB scratch FETCH). No LDS/barriers in
// the K-loop. IN-PLACE HAZARD (round-7 lesson): when out==A, wave 0's store
// of cols 0..11 raced wave 7's loads of k=0..11 -> one __syncthreads between
// K-loop and store (all A-reads are consumed into acc by then).
// MODE0: fused edge histogram (2 atomics/thread) drains under the K-loop.
// Col stats: 64-lane shfl butterfly; MODE2 row-sumsq: [8][64] LDS.
template<int K, int MODE>
__global__ __launch_bounds__(512) void gemm_sw(
    const float* __restrict__ A, const float* __restrict__ W, const float* __restrict__ bias,
    float* __restrict__ out, const float* __restrict__ scale, const float* __restrict__ shift,
    float* __restrict__ gsum, float* __restrict__ gsumsq,
    float* __restrict__ gcol, float* __restrict__ growss,
    const int* __restrict__ ei, int* __restrict__ hist_cnt, int E)
{
    __shared__ float rss[8][64];           // MODE2 epilogue only (2 KB)
    const int tid  = threadIdx.x;
    const int lane = tid & 63;
    const int wid  = tid >> 6;             // 0..7
    const int cb   = __builtin_amdgcn_readfirstlane(wid * 12);   // uniform col base
    const int row  = blockIdx.x * 64 + lane;
    const bool rok = row < NN;

    if (MODE == 0) {                       // fused histogram: 2 edges/thread
        int e0 = (blockIdx.x * 512 + tid) * 2;
        if (e0 + 2 <= E) {
            int2 d2 = *(const int2*)(ei + E + e0);
            atomicAdd(&hist_cnt[d2.x], 1);
            atomicAdd(&hist_cnt[d2.y], 1);
        } else if (e0 < E) {
            atomicAdd(&hist_cnt[ei[E + e0]], 1);
        }
    }

    const float* Wp = W + (size_t)cb * K;  // uniform pointer
    const float* Ap = A + (size_t)row * K;

    float acc[12];
#pragma unroll
    for (int j = 0; j < 12; ++j) acc[j] = 0.f;

    constexpr int NB = K / 16;             // 16-kk batches
    float4 pa[4], pb[4];
#pragma unroll
    for (int u = 0; u < 4; ++u)
        pa[u] = rok ? ld4(Ap + u * 4) : make_float4(0.f, 0.f, 0.f, 0.f);

#pragma unroll
    for (int b = 0; b < NB; ++b) {
        if (b + 1 < NB) {                  // prefetch next 16-kk batch
#pragma unroll
            for (int u = 0; u < 4; ++u)
                pb[u] = rok ? ld4(Ap + (b + 1) * 16 + u * 4)
                            : make_float4(0.f, 0.f, 0.f, 0.f);
        }
#pragma unroll
        for (int u = 0; u < 4; ++u) {
            const int kc = b * 16 + u * 4;
            float av[4];
            if (MODE == 2) {
                float4 sc = ld4(scale + kc), sh = ld4(shift + kc);   // uniform
                av[0] = fmaxf(pa[u].x * sc.x + sh.x, 0.f);
                av[1] = fmaxf(pa[u].y * sc.y + sh.y, 0.f);
                av[2] = fmaxf(pa[u].z * sc.z + sh.z, 0.f);
                av[3] = fmaxf(pa[u].w * sc.w + sh.w, 0.f);
            } else {
                av[0] = pa[u].x; av[1] = pa[u].y; av[2] = pa[u].z; av[3] = pa[u].w;
            }
#pragma unroll
            for (int j = 0; j < 12; ++j) {
                float4 w4 = ld4(Wp + j * K + kc);     // wave-uniform -> s_load
                acc[j] = fmaf(av[0], w4.x, acc[j]);
                acc[j] = fmaf(av[1], w4.y, acc[j]);
                acc[j] = fmaf(av[2], w4.z, acc[j]);
                acc[j] = fmaf(av[3], w4.w, acc[j]);
            }
        }
#pragma unroll
        for (int u = 0; u < 4; ++u) pa[u] = pb[u];
    }

    // In-place WAR fence: every wave's A-reads are consumed into acc above;
    // no store may happen until all waves pass this point (out may alias A).
    if (MODE != 0) __syncthreads();

    // ---- epilogue ----
    float cv[12];
    {
        float4 b0 = ld4(bias + cb), b1 = ld4(bias + cb + 4), b2 = ld4(bias + cb + 8);
        float bv[12] = {b0.x, b0.y, b0.z, b0.w, b1.x, b1.y, b1.z, b1.w,
                        b2.x, b2.y, b2.z, b2.w};
#pragma unroll
        for (int j = 0; j < 12; ++j) cv[j] = acc[j] + bv[j];
    }
    if (rok) {
        float* o = out + (size_t)row * HD + cb;
        *(float4*)(o + 0) = make_float4(cv[0], cv[1], cv[2],  cv[3]);
        *(float4*)(o + 4) = make_float4(cv[4], cv[5], cv[6],  cv[7]);
        *(float4*)(o + 8) = make_float4(cv[8], cv[9], cv[10], cv[11]);
    }

    if (MODE == 1) {
        float s[12], q[12];
#pragma unroll
        for (int j = 0; j < 12; ++j) {
            float v = rok ? cv[j] : 0.f;
            s[j] = v; q[j] = v * v;
        }
#pragma unroll
        for (int d = 1; d <= 32; d <<= 1)
#pragma unroll
            for (int j = 0; j < 12; ++j) {
                s[j] += __shfl_xor(s[j], d);
                q[j] += __shfl_xor(q[j], d);
            }
        if (lane == 0) {
#pragma unroll
            for (int j = 0; j < 12; ++j) {
                atomicAdd(&gsum[cb + j], s[j]);
                atomicAdd(&gsumsq[cb + j], q[j]);
            }
        }
    }

    if (MODE == 2) {
        float s[12];
#pragma unroll
        for (int j = 0; j < 12; ++j) s[j] = rok ? cv[j] : 0.f;
#pragma unroll
        for (int d = 1; d <= 32; d <<= 1)
#pragma unroll
            for (int j = 0; j < 12; ++j) s[j] += __shfl_xor(s[j], d);
        if (lane == 0) {
#pragma unroll
            for (int j = 0; j < 12; ++j) atomicAdd(&gcol[cb + j], s[j]);
        }
        float rq = 0.f;
#pragma unroll
        for (int j = 0; j < 12; ++j) rq = fmaf(cv[j], cv[j], rq);
        rss[wid][lane] = rq;
        __syncthreads();
        if (wid == 0 && rok) {
            float S = 0.f;
#pragma unroll
            for (int g = 0; g < 8; ++g) S += rss[g][lane];
            growss[row] = S;
        }
    }
}

// ---------------- CSR build ----------------
__global__ __launch_bounds__(256) void scan_part1(const int* __restrict__ cnt,
                                                  int* __restrict__ bsum) {
    __shared__ int sh[256];
    int i = blockIdx.x * 256 + threadIdx.x;
    int t = threadIdx.x;
    sh[t] = (i < NN) ? cnt[i] : 0;
    __syncthreads();
    for (int off = 128; off > 0; off >>= 1) {
        if (t < off) sh[t] += sh[t + off];
        __syncthreads();
    }
    if (t == 0) bsum[blockIdx.x] = sh[0];
}

__global__ __launch_bounds__(256) void scan_part2(int* __restrict__ bsum) {
    __shared__ int sh[256];
    int t = threadIdx.x;
    int v = (t < SCAN_NB) ? bsum[t] : 0;
    sh[t] = v;
    __syncthreads();
    for (int off = 1; off < 256; off <<= 1) {
        int u = sh[t];
        if (t >= off) u += sh[t - off];
        __syncthreads();
        sh[t] = u;
        __syncthreads();
    }
    if (t < SCAN_NB) bsum[t] = sh[t] - v;    // exclusive block offsets
}

__global__ __launch_bounds__(256) void scan_part3(int* __restrict__ cnt,
                                                  const int* __restrict__ bsum,
                                                  int* __restrict__ rowptr) {
    __shared__ int sh[256];
    int i = blockIdx.x * 256 + threadIdx.x;
    int t = threadIdx.x;
    int v = (i < NN) ? cnt[i] : 0;
    sh[t] = v;
    __syncthreads();
    for (int off = 1; off < 256; off <<= 1) {
        int u = sh[t];
        if (t >= off) u += sh[t - off];
        __syncthreads();
        sh[t] = u;
        __syncthreads();
    }
    int excl = sh[t] - v + bsum[blockIdx.x];
    if (i < NN) { rowptr[i] = excl; cnt[i] = excl; }   // cnt becomes fill cursor
    if (i == NN - 1) rowptr[NN] = excl + v;
}

// fill with dst-range multipass: clusters slot-writes of a row in time so the
// srcs write window per pass (~460 KB) stays L2-resident -> line coalescing.
// (Round-1 A/B: removing the pass clustering raised WRITE_SIZE 40->52.6 MB and
// slowed fill 46.5->55 us despite 2x occupancy -> clustering is load-bearing.)
__global__ __launch_bounds__(256) void fill_kernel(const int* __restrict__ ei,
                                                   int* __restrict__ cursor,
                                                   int* __restrict__ srcs, int E) {
    int t2 = blockIdx.x * 256 + threadIdx.x;
    int e0 = t2 * 2;
    int src[2], dst[2];
#pragma unroll
    for (int i = 0; i < 2; ++i) {
        int e = e0 + i;
        bool ok = e < E;
        dst[i] = ok ? ei[E + e] : -1;
        src[i] = ok ? ei[e] : 0;
    }
    for (int pass = 0; pass < 7; ++pass) {
#pragma unroll
        for (int i = 0; i < 2; ++i) {
            if (dst[i] >= 0 && (dst[i] >> 13) == pass) {
                int slot = atomicAdd(&cursor[dst[i]], 1);
                srcs[slot] = src[i];
            }
        }
    }
}

// -------- gather: z[i] = h0[i] + sum_{e:dst=i} h0[src_e] --------------------
// One 24-lane group owns a full row (24 x float4 = 96 floats). No LDS, no
// __syncthreads: waves retire independently, 8-deep load batches give MLP.
__global__ __launch_bounds__(192) void gather_kernel(
    const float* __restrict__ h0, const int* __restrict__ rowptr,
    const int* __restrict__ srcs, float* __restrict__ z)
{
    const int tid = threadIdx.x;
    const int rl  = tid / 24;          // 0..7 local row
    const int c   = tid - rl * 24;     // 0..23 float4 lane
    const int row = blockIdx.x * 8 + rl;
    if (row >= NN) return;

    const int p0 = rowptr[row];
    const int p1 = rowptr[row + 1];

    float4 acc = ld4(h0 + (size_t)row * HD + c * 4);

    int p = p0;
    for (; p + 8 <= p1; p += 8) {
        int s0 = srcs[p + 0], s1 = srcs[p + 1], s2 = srcs[p + 2], s3 = srcs[p + 3];
        int s4 = srcs[p + 4], s5 = srcs[p + 5], s6 = srcs[p + 6], s7 = srcs[p + 7];
        float4 v0 = ld4(h0 + (size_t)s0 * HD + c * 4);
        float4 v1 = ld4(h0 + (size_t)s1 * HD + c * 4);
        float4 v2 = ld4(h0 + (size_t)s2 * HD + c * 4);
        float4 v3 = ld4(h0 + (size_t)s3 * HD + c * 4);
        float4 v4 = ld4(h0 + (size_t)s4 * HD + c * 4);
        float4 v5 = ld4(h0 + (size_t)s5 * HD + c * 4);
        float4 v6 = ld4(h0 + (size_t)s6 * HD + c * 4);
        float4 v7 = ld4(h0 + (size_t)s7 * HD + c * 4);
        acc = add4(acc, add4(add4(add4(v0, v1), add4(v2, v3)),
                             add4(add4(v4, v5), add4(v6, v7))));
    }
    for (; p + 4 <= p1; p += 4) {
        int s0 = srcs[p + 0], s1 = srcs[p + 1], s2 = srcs[p + 2], s3 = srcs[p + 3];
        float4 v0 = ld4(h0 + (size_t)s0 * HD + c * 4);
        float4 v1 = ld4(h0 + (size_t)s1 * HD + c * 4);
        float4 v2 = ld4(h0 + (size_t)s2 * HD + c * 4);
        float4 v3 = ld4(h0 + (size_t)s3 * HD + c * 4);
        acc = add4(acc, add4(add4(v0, v1), add4(v2, v3)));
    }
    for (; p < p1; ++p)
        acc = add4(acc, ld4(h0 + (size_t)srcs[p] * HD + c * 4));

    *(float4*)(z + (size_t)row * HD + c * 4) = acc;
}

__global__ void bn_finalize_kernel(const float* __restrict__ sum, const float* __restrict__ sumsq,
                                   const float* __restrict__ gamma, const float* __restrict__ beta,
                                   float* __restrict__ scale, float* __restrict__ shift)
{
    int f = threadIdx.x;
    if (f < HD) {
        float mean = sum[f] * (1.0f / NN);
        float var  = fmaxf(sumsq[f] * (1.0f / NN) - mean * mean, 0.0f);
        float rstd = rsqrtf(var + BN_EPS);
        float sc = rstd * gamma[f];
        scale[f] = sc;
        shift[f] = beta[f] - mean * sc;
    }
}

// ---------------- PairNorm: streaming float4, in place ----------------
__global__ __launch_bounds__(256) void pn_kernel(float* l1, const float* __restrict__ colsum,
                                                 const float* __restrict__ rowss)
{
    int idx = blockIdx.x * 256 + threadIdx.x;   // float4 index
    if (idx >= NN * 24) return;
    int row = idx / 24;
    int q = idx - row * 24;
    float rs = rsqrtf(1e-6f + rowss[row]);
    float4 v = ld4(l1 + (size_t)idx * 4);
    float4 cm = ld4(colsum + q * 4);
    v.x = PN_SCALE * v.x * rs - cm.x * (1.0f / NN);
    v.y = PN_SCALE * v.y * rs - cm.y * (1.0f / NN);
    v.z = PN_SCALE * v.z * rs - cm.z * (1.0f / NN);
    v.w = PN_SCALE * v.w * rs - cm.w * (1.0f / NN);
    *(float4*)(l1 + (size_t)idx * 4) = v;
}

extern "C" void kernel_launch(void* const* d_in, const int* in_sizes, int n_in,
                              void* d_out, int out_size, void* d_ws, size_t ws_size,
                              hipStream_t stream) {
    const float* x     = (const float*)d_in[0];
    const int*   ei    = (const int*)d_in[1];
    const float* W0    = (const float*)d_in[2];
    const float* b0    = (const float*)d_in[3];
    const float* W1    = (const float*)d_in[4];
    const float* b1    = (const float*)d_in[5];
    const float* gamma = (const float*)d_in[6];
    const float* beta  = (const float*)d_in[7];
    const float* W2    = (const float*)d_in[8];
    const float* b2    = (const float*)d_in[9];

    float* out_l1 = (float*)d_out;                 // [N,96]: z -> h -> l1 (in place)
    float* out_h0 = out_l1 + (size_t)NN * HD;      // [N,96]: h0 output

    float* stats   = (float*)d_ws;
    float* s_sum   = stats;            // 96
    float* s_sumsq = stats + HD;       // 96
    float* s_col   = stats + 2 * HD;   // 96
    float* s_scale = stats + 288;      // 96
    float* s_shift = stats + 384;      // 96
    float* rowss = stats + 1024;
    int* cnt    = (int*)(rowss + NN);
    int* rowptr = cnt + NN;
    int* bsum   = rowptr + NN + 2;
    int* srcs   = bsum + 256;

    const int E = in_sizes[1] / 2;                 // 800000
    const int GB = (NN + 63) / 64;                 // 782

    zero_kernel<<<(1024 + NN + 255) / 256, 256, 0, stream>>>(stats, cnt);
    // 1) h0 = x @ W0^T + b0, edge histogram fused (2 atomics/thread)
    gemm_sw<IN_DIM, 0><<<GB, 512, 0, stream>>>(x, W0, b0, out_h0, nullptr, nullptr,
                                               nullptr, nullptr, nullptr, nullptr,
                                               ei, cnt, E);
    // 2) CSR build: hierarchical scan -> multipass fill
    scan_part1<<<SCAN_NB, 256, 0, stream>>>(cnt, bsum);
    scan_part2<<<1, 256, 0, stream>>>(bsum);
    scan_part3<<<SCAN_NB, 256, 0, stream>>>(cnt, bsum, rowptr);
    fill_kernel<<<(E / 2 + 255) / 256, 256, 0, stream>>>(ei, cnt, srcs, E);
    // 3) gather: z = h0 + segment_sum(h0[src])
    gather_kernel<<<(NN + 7) / 8, 192, 0, stream>>>(out_h0, rowptr, srcs, out_l1);
    // 4) h = z @ W1^T + b1 (in place) + fused BN stats
    gemm_sw<HD, 1><<<GB, 512, 0, stream>>>(out_l1, W1, b1, out_l1, nullptr, nullptr,
                                           s_sum, s_sumsq, nullptr, nullptr,
                                           nullptr, nullptr, 0);
    bn_finalize_kernel<<<1, 128, 0, stream>>>(s_sum, s_sumsq, gamma, beta, s_scale, s_shift);
    // 5) l1 = relu(bn(h)) @ W2^T + b2 (in place) + fused PN stats
    gemm_sw<HD, 2><<<GB, 512, 0, stream>>>(out_l1, W2, b2, out_l1, s_scale, s_shift,
                                           nullptr, nullptr, s_col, rowss,
                                           nullptr, nullptr, 0);
    // 6) PairNorm finalize (streaming, in place)
    pn_kernel<<<(NN * 24 + 255) / 256, 256, 0, stream>>>(out_l1, s_col, rowss);
}

// Round 9
// 329.588 us; speedup vs baseline: 12.8951x; 2.8536x over previous
//
#include <hip/hip_runtime.h>

#define NN 50000
#define IN_DIM 128
#define HD 96
#define BN_EPS 1e-5f
#define PN_SCALE 20.0f
#define SCAN_NB 196   // ceil(50000/256)

__device__ __forceinline__ float4 ld4(const float* p) { return *(const float4*)p; }
__device__ __forceinline__ float4 add4(float4 a, float4 b) {
    return make_float4(a.x + b.x, a.y + b.y, a.z + b.z, a.w + b.w);
}

// ---------------- zero stats + CSR counters ----------------
__global__ void zero_kernel(float* stats, int* cnt) {
    int i = blockIdx.x * blockDim.x + threadIdx.x;
    if (i < 1024) stats[i] = 0.0f;
    int j = i - 1024;
    if (j >= 0 && j < NN) cnt[j] = 0;
}

// ---------------- tiled GEMM: C[N,96] = act(A[N,K]) @ W[96,K]^T + b ----------
// Proven round-3 structure (k-major LDS, reg-staged prefetch, barrier/chunk)
// with thread tile 2x12 -> 4x12: per kk = 4x ds_read_b128 (1 A + 3 W) for 48
// FMAs -> LDS port ~48cyc vs 48 CU-VALU-cyc (was 44:24, LDS-bound 2x).
// 128 threads = 16 ty (4 rows) x 8 tx (12 cols), BM=64 -> 782 blocks (~3/CU).
// Read banks conflict-free: A addrs ty*16B cover 32 banks w/ 8-lane bcast;
// W addrs (tx*48+m*16)B cover all 32 banks once. acc 48 + staging ~40 VGPR,
// no spill (round-6: spill = 987MB scratch; round-8: scalar-W loads = latency
// chain, 345us). In-place safe: all A-reads staged before epilogue stores.
// MODE 0 fuses the edge histogram (8 atomics/thread drain under K-loop).
template<int K, int MODE>
__global__ __launch_bounds__(128) void gemm_tiled(
    const float* A, const float* __restrict__ W, const float* __restrict__ bias,
    float* out, const float* __restrict__ scale, const float* __restrict__ shift,
    float* __restrict__ gsum, float* __restrict__ gsumsq,
    float* __restrict__ gcol, float* __restrict__ growss,
    const int* __restrict__ ei, int* __restrict__ hist_cnt, int E)
{
    constexpr int CK  = 32;
    constexpr int APD = 68;    // As row pitch (64+4): 272B, 16B-aligned rows
    constexpr int WPD = 100;   // Ws row pitch (96+4): 400B, 16B-aligned rows
    __shared__ float sh[CK * APD + CK * WPD];   // 21504 B
    float* As = sh;              // [kk][row] k-major
    float* Ws = sh + CK * APD;   // [kk][col] k-major

    const int t  = threadIdx.x;   // 0..127
    const int tx = t & 7;         // cols tx*12 .. +11
    const int ty = t >> 3;        // rows ty*4 .. +3
    const int base = blockIdx.x * 64;

    if (MODE == 0) {              // fused histogram: 8 edges/thread
        int e0 = (blockIdx.x * 128 + t) * 8;
        if (e0 + 8 <= E) {
            int4 a4 = *(const int4*)(ei + E + e0);
            int4 b4 = *(const int4*)(ei + E + e0 + 4);
            atomicAdd(&hist_cnt[a4.x], 1); atomicAdd(&hist_cnt[a4.y], 1);
            atomicAdd(&hist_cnt[a4.z], 1); atomicAdd(&hist_cnt[a4.w], 1);
            atomicAdd(&hist_cnt[b4.x], 1); atomicAdd(&hist_cnt[b4.y], 1);
            atomicAdd(&hist_cnt[b4.z], 1); atomicAdd(&hist_cnt[b4.w], 1);
        } else {
            for (int i = 0; i < 8; ++i) {
                int e = e0 + i;
                if (e < E) atomicAdd(&hist_cnt[ei[E + e]], 1);
            }
        }
    }

    float acc[4][12];
#pragma unroll
    for (int i = 0; i < 4; ++i)
#pragma unroll
        for (int j = 0; j < 12; ++j) acc[i][j] = 0.0f;

    float4 pa[4], pw[6];

    auto load_stage = [&](int kc) {
#pragma unroll
        for (int it = 0; it < 4; ++it) {
            int q = t + it * 128;
            int r = q >> 3, c4 = q & 7;
            int row = base + r;
            pa[it] = (row < NN) ? ld4(A + (size_t)row * K + kc + c4 * 4)
                                : make_float4(0.f, 0.f, 0.f, 0.f);
        }
#pragma unroll
        for (int it = 0; it < 6; ++it) {
            int q = t + it * 128;
            int col = q >> 3, c4 = q & 7;     // col < 96
            pw[it] = ld4(W + (size_t)col * K + kc + c4 * 4);
        }
    };

    auto write_stage = [&](int kc) {
#pragma unroll
        for (int it = 0; it < 4; ++it) {
            int q = t + it * 128;
            int r = q >> 3, c4 = q & 7;
            float4 v = pa[it];
            if (MODE == 2) {
                float4 sc  = ld4(scale + kc + c4 * 4);
                float4 shf = ld4(shift + kc + c4 * 4);
                v.x = fmaxf(v.x * sc.x + shf.x, 0.f);
                v.y = fmaxf(v.y * sc.y + shf.y, 0.f);
                v.z = fmaxf(v.z * sc.z + shf.z, 0.f);
                v.w = fmaxf(v.w * sc.w + shf.w, 0.f);
            }
            As[(c4 * 4 + 0) * APD + r] = v.x;
            As[(c4 * 4 + 1) * APD + r] = v.y;
            As[(c4 * 4 + 2) * APD + r] = v.z;
            As[(c4 * 4 + 3) * APD + r] = v.w;
        }
#pragma unroll
        for (int it = 0; it < 6; ++it) {
            int q = t + it * 128;
            int col = q >> 3, c4 = q & 7;
            float4 v = pw[it];
            Ws[(c4 * 4 + 0) * WPD + col] = v.x;
            Ws[(c4 * 4 + 1) * WPD + col] = v.y;
            Ws[(c4 * 4 + 2) * WPD + col] = v.z;
            Ws[(c4 * 4 + 3) * WPD + col] = v.w;
        }
    };

    load_stage(0);
    for (int kc = 0; kc < K; kc += CK) {
        write_stage(kc);
        __syncthreads();
        if (kc + CK < K) load_stage(kc + CK);   // in flight during compute
#pragma unroll 8
        for (int kk = 0; kk < CK; ++kk) {
            float4 a  = ld4(As + kk * APD + ty * 4);
            float4 w0 = ld4(Ws + kk * WPD + tx * 12);
            float4 w1 = ld4(Ws + kk * WPD + tx * 12 + 4);
            float4 w2 = ld4(Ws + kk * WPD + tx * 12 + 8);
            float av[4] = {a.x, a.y, a.z, a.w};
            float wv[12] = {w0.x, w0.y, w0.z, w0.w,
                            w1.x, w1.y, w1.z, w1.w,
                            w2.x, w2.y, w2.z, w2.w};
#pragma unroll
            for (int i = 0; i < 4; ++i)
#pragma unroll
                for (int j = 0; j < 12; ++j)
                    acc[i][j] = fmaf(av[i], wv[j], acc[i][j]);
        }
        __syncthreads();
    }

    // ---- epilogue: bias, store, fused stats ----
    float cv[4][12];
    {
        float4 b0 = ld4(bias + tx * 12), b1 = ld4(bias + tx * 12 + 4),
               b2 = ld4(bias + tx * 12 + 8);
        float bv[12] = {b0.x, b0.y, b0.z, b0.w, b1.x, b1.y, b1.z, b1.w,
                        b2.x, b2.y, b2.z, b2.w};
#pragma unroll
        for (int i = 0; i < 4; ++i)
#pragma unroll
            for (int j = 0; j < 12; ++j) cv[i][j] = acc[i][j] + bv[j];
    }
#pragma unroll
    for (int i = 0; i < 4; ++i) {
        int row = base + ty * 4 + i;
        if (row < NN) {
            float* o = out + (size_t)row * HD + tx * 12;
            *(float4*)(o + 0) = make_float4(cv[i][0], cv[i][1], cv[i][2],  cv[i][3]);
            *(float4*)(o + 4) = make_float4(cv[i][4], cv[i][5], cv[i][6],  cv[i][7]);
            *(float4*)(o + 8) = make_float4(cv[i][8], cv[i][9], cv[i][10], cv[i][11]);
        }
    }

    if (MODE == 1) {
        float* rs_sum = sh;            // [16][96]
        float* rs_sq  = sh + 1536;     // [16][96]
        float s[12], q[12];
#pragma unroll
        for (int j = 0; j < 12; ++j) {
            s[j] = 0.f; q[j] = 0.f;
#pragma unroll
            for (int i = 0; i < 4; ++i) {
                int row = base + ty * 4 + i;
                float v = (row < NN) ? cv[i][j] : 0.f;
                s[j] += v; q[j] += v * v;
            }
        }
#pragma unroll
        for (int j = 0; j < 12; ++j) {
            rs_sum[ty * HD + tx * 12 + j] = s[j];
            rs_sq[ty * HD + tx * 12 + j]  = q[j];
        }
        __syncthreads();
        if (t < HD) {
            float S = 0.f, Q = 0.f;
#pragma unroll
            for (int r = 0; r < 16; ++r) { S += rs_sum[r * HD + t]; Q += rs_sq[r * HD + t]; }
            atomicAdd(&gsum[t], S);
            atomicAdd(&gsumsq[t], Q);
        }
    }

    if (MODE == 2) {
        float* rs_sum = sh;            // [16][96]
        float* rr     = sh + 1536;     // [64][8]
        float s[12];
#pragma unroll
        for (int j = 0; j < 12; ++j) {
            s[j] = 0.f;
#pragma unroll
            for (int i = 0; i < 4; ++i) {
                int row = base + ty * 4 + i;
                s[j] += (row < NN) ? cv[i][j] : 0.f;
            }
        }
#pragma unroll
        for (int j = 0; j < 12; ++j)
            rs_sum[ty * HD + tx * 12 + j] = s[j];
#pragma unroll
        for (int i = 0; i < 4; ++i) {
            float q = 0.f;
#pragma unroll
            for (int j = 0; j < 12; ++j) q = fmaf(cv[i][j], cv[i][j], q);
            rr[(ty * 4 + i) * 8 + tx] = q;
        }
        __syncthreads();
        if (t < HD) {
            float S = 0.f;
#pragma unroll
            for (int r = 0; r < 16; ++r) S += rs_sum[r * HD + t];
            atomicAdd(&gcol[t], S);
        }
        if (t < 64) {
            int row = base + t;
            if (row < NN) {
                float S = 0.f;
#pragma unroll
                for (int g = 0; g < 8; ++g) S += rr[t * 8 + g];
                growss[row] = S;
            }
        }
    }
}

// ---------------- CSR build ----------------
__global__ __launch_bounds__(256) void scan_part1(const int* __restrict__ cnt,
                                                  int* __restrict__ bsum) {
    __shared__ int sh[256];
    int i = blockIdx.x * 256 + threadIdx.x;
    int t = threadIdx.x;
    sh[t] = (i < NN) ? cnt[i] : 0;
    __syncthreads();
    for (int off = 128; off > 0; off >>= 1) {
        if (t < off) sh[t] += sh[t + off];
        __syncthreads();
    }
    if (t == 0) bsum[blockIdx.x] = sh[0];
}

__global__ __launch_bounds__(256) void scan_part2(int* __restrict__ bsum) {
    __shared__ int sh[256];
    int t = threadIdx.x;
    int v = (t < SCAN_NB) ? bsum[t] : 0;
    sh[t] = v;
    __syncthreads();
    for (int off = 1; off < 256; off <<= 1) {
        int u = sh[t];
        if (t >= off) u += sh[t - off];
        __syncthreads();
        sh[t] = u;
        __syncthreads();
    }
    if (t < SCAN_NB) bsum[t] = sh[t] - v;    // exclusive block offsets
}

__global__ __launch_bounds__(256) void scan_part3(int* __restrict__ cnt,
                                                  const int* __restrict__ bsum,
                                                  int* __restrict__ rowptr) {
    __shared__ int sh[256];
    int i = blockIdx.x * 256 + threadIdx.x;
    int t = threadIdx.x;
    int v = (i < NN) ? cnt[i] : 0;
    sh[t] = v;
    __syncthreads();
    for (int off = 1; off < 256; off <<= 1) {
        int u = sh[t];
        if (t >= off) u += sh[t - off];
        __syncthreads();
        sh[t] = u;
        __syncthreads();
    }
    int excl = sh[t] - v + bsum[blockIdx.x];
    if (i < NN) { rowptr[i] = excl; cnt[i] = excl; }   // cnt becomes fill cursor
    if (i == NN - 1) rowptr[NN] = excl + v;
}

// fill with dst-range multipass: clusters slot-writes of a row in time so the
// srcs write window per pass (~460 KB) stays L2-resident -> line coalescing.
// (Round-1 A/B: removing the pass clustering raised WRITE_SIZE 40->52.6 MB and
// slowed fill 46.5->55 us despite 2x occupancy -> clustering is load-bearing.)
__global__ __launch_bounds__(256) void fill_kernel(const int* __restrict__ ei,
                                                   int* __restrict__ cursor,
                                                   int* __restrict__ srcs, int E) {
    int t2 = blockIdx.x * 256 + threadIdx.x;
    int e0 = t2 * 2;
    int src[2], dst[2];
#pragma unroll
    for (int i = 0; i < 2; ++i) {
        int e = e0 + i;
        bool ok = e < E;
        dst[i] = ok ? ei[E + e] : -1;
        src[i] = ok ? ei[e] : 0;
    }
    for (int pass = 0; pass < 7; ++pass) {
#pragma unroll
        for (int i = 0; i < 2; ++i) {
            if (dst[i] >= 0 && (dst[i] >> 13) == pass) {
                int slot = atomicAdd(&cursor[dst[i]], 1);
                srcs[slot] = src[i];
            }
        }
    }
}

// -------- gather: z[i] = h0[i] + sum_{e:dst=i} h0[src_e] --------------------
// One 24-lane group owns a full row (24 x float4 = 96 floats). No LDS, no
// __syncthreads: waves retire independently, 8-deep load batches give MLP.
__global__ __launch_bounds__(192) void gather_kernel(
    const float* __restrict__ h0, const int* __restrict__ rowptr,
    const int* __restrict__ srcs, float* __restrict__ z)
{
    const int tid = threadIdx.x;
    const int rl  = tid / 24;          // 0..7 local row
    const int c   = tid - rl * 24;     // 0..23 float4 lane
    const int row = blockIdx.x * 8 + rl;
    if (row >= NN) return;

    const int p0 = rowptr[row];
    const int p1 = rowptr[row + 1];

    float4 acc = ld4(h0 + (size_t)row * HD + c * 4);

    int p = p0;
    for (; p + 8 <= p1; p += 8) {
        int s0 = srcs[p + 0], s1 = srcs[p + 1], s2 = srcs[p + 2], s3 = srcs[p + 3];
        int s4 = srcs[p + 4], s5 = srcs[p + 5], s6 = srcs[p + 6], s7 = srcs[p + 7];
        float4 v0 = ld4(h0 + (size_t)s0 * HD + c * 4);
        float4 v1 = ld4(h0 + (size_t)s1 * HD + c * 4);
        float4 v2 = ld4(h0 + (size_t)s2 * HD + c * 4);
        float4 v3 = ld4(h0 + (size_t)s3 * HD + c * 4);
        float4 v4 = ld4(h0 + (size_t)s4 * HD + c * 4);
        float4 v5 = ld4(h0 + (size_t)s5 * HD + c * 4);
        float4 v6 = ld4(h0 + (size_t)s6 * HD + c * 4);
        float4 v7 = ld4(h0 + (size_t)s7 * HD + c * 4);
        acc = add4(acc, add4(add4(add4(v0, v1), add4(v2, v3)),
                             add4(add4(v4, v5), add4(v6, v7))));
    }
    for (; p + 4 <= p1; p += 4) {
        int s0 = srcs[p + 0], s1 = srcs[p + 1], s2 = srcs[p + 2], s3 = srcs[p + 3];
        float4 v0 = ld4(h0 + (size_t)s0 * HD + c * 4);
        float4 v1 = ld4(h0 + (size_t)s1 * HD + c * 4);
        float4 v2 = ld4(h0 + (size_t)s2 * HD + c * 4);
        float4 v3 = ld4(h0 + (size_t)s3 * HD + c * 4);
        acc = add4(acc, add4(add4(v0, v1), add4(v2, v3)));
    }
    for (; p < p1; ++p)
        acc = add4(acc, ld4(h0 + (size_t)srcs[p] * HD + c * 4));

    *(float4*)(z + (size_t)row * HD + c * 4) = acc;
}

__global__ void bn_finalize_kernel(const float* __restrict__ sum, const float* __restrict__ sumsq,
                                   const float* __restrict__ gamma, const float* __restrict__ beta,
                                   float* __restrict__ scale, float* __restrict__ shift)
{
    int f = threadIdx.x;
    if (f < HD) {
        float mean = sum[f] * (1.0f / NN);
        float var  = fmaxf(sumsq[f] * (1.0f / NN) - mean * mean, 0.0f);
        float rstd = rsqrtf(var + BN_EPS);
        float sc = rstd * gamma[f];
        scale[f] = sc;
        shift[f] = beta[f] - mean * sc;
    }
}

// ---------------- PairNorm: streaming float4, in place ----------------
__global__ __launch_bounds__(256) void pn_kernel(float* l1, const float* __restrict__ colsum,
                                                 const float* __restrict__ rowss)
{
    int idx = blockIdx.x * 256 + threadIdx.x;   // float4 index
    if (idx >= NN * 24) return;
    int row = idx / 24;
    int q = idx - row * 24;
    float rs = rsqrtf(1e-6f + rowss[row]);
    float4 v = ld4(l1 + (size_t)idx * 4);
    float4 cm = ld4(colsum + q * 4);
    v.x = PN_SCALE * v.x * rs - cm.x * (1.0f / NN);
    v.y = PN_SCALE * v.y * rs - cm.y * (1.0f / NN);
    v.z = PN_SCALE * v.z * rs - cm.z * (1.0f / NN);
    v.w = PN_SCALE * v.w * rs - cm.w * (1.0f / NN);
    *(float4*)(l1 + (size_t)idx * 4) = v;
}

extern "C" void kernel_launch(void* const* d_in, const int* in_sizes, int n_in,
                              void* d_out, int out_size, void* d_ws, size_t ws_size,
                              hipStream_t stream) {
    const float* x     = (const float*)d_in[0];
    const int*   ei    = (const int*)d_in[1];
    const float* W0    = (const float*)d_in[2];
    const float* b0    = (const float*)d_in[3];
    const float* W1    = (const float*)d_in[4];
    const float* b1    = (const float*)d_in[5];
    const float* gamma = (const float*)d_in[6];
    const float* beta  = (const float*)d_in[7];
    const float* W2    = (const float*)d_in[8];
    const float* b2    = (const float*)d_in[9];

    float* out_l1 = (float*)d_out;                 // [N,96]: z -> h -> l1 (in place)
    float* out_h0 = out_l1 + (size_t)NN * HD;      // [N,96]: h0 output

    float* stats   = (float*)d_ws;
    float* s_sum   = stats;            // 96
    float* s_sumsq = stats + HD;       // 96
    float* s_col   = stats + 2 * HD;   // 96
    float* s_scale = stats + 288;      // 96
    float* s_shift = stats + 384;      // 96
    float* rowss = stats + 1024;
    int* cnt    = (int*)(rowss + NN);
    int* rowptr = cnt + NN;
    int* bsum   = rowptr + NN + 2;
    int* srcs   = bsum + 256;

    const int E = in_sizes[1] / 2;                 // 800000
    const int GB = (NN + 63) / 64;                 // 782

    zero_kernel<<<(1024 + NN + 255) / 256, 256, 0, stream>>>(stats, cnt);
    // 1) h0 = x @ W0^T + b0, edge histogram fused (8 atomics/thread)
    gemm_tiled<IN_DIM, 0><<<GB, 128, 0, stream>>>(x, W0, b0, out_h0, nullptr, nullptr,
                                                  nullptr, nullptr, nullptr, nullptr,
                                                  ei, cnt, E);
    // 2) CSR build: hierarchical scan -> multipass fill
    scan_part1<<<SCAN_NB, 256, 0, stream>>>(cnt, bsum);
    scan_part2<<<1, 256, 0, stream>>>(bsum);
    scan_part3<<<SCAN_NB, 256, 0, stream>>>(cnt, bsum, rowptr);
    fill_kernel<<<(E / 2 + 255) / 256, 256, 0, stream>>>(ei, cnt, srcs, E);
    // 3) gather: z = h0 + segment_sum(h0[src])
    gather_kernel<<<(NN + 7) / 8, 192, 0, stream>>>(out_h0, rowptr, srcs, out_l1);
    // 4) h = z @ W1^T + b1 (in place) + fused BN stats
    gemm_tiled<HD, 1><<<GB, 128, 0, stream>>>(out_l1, W1, b1, out_l1, nullptr, nullptr,
                                              s_sum, s_sumsq, nullptr, nullptr,
                                              nullptr, nullptr, 0);
    bn_finalize_kernel<<<1, 128, 0, stream>>>(s_sum, s_sumsq, gamma, beta, s_scale, s_shift);
    // 5) l1 = relu(bn(h)) @ W2^T + b2 (in place) + fused PN stats
    gemm_tiled<HD, 2><<<GB, 128, 0, stream>>>(out_l1, W2, b2, out_l1, s_scale, s_shift,
                                              nullptr, nullptr, s_col, rowss,
                                              nullptr, nullptr, 0);
    // 6) PairNorm finalize (streaming, in place)
    pn_kernel<<<(NN * 24 + 255) / 256, 256, 0, stream>>>(out_l1, s_col, rowss);
}

// Round 10
// 306.262 us; speedup vs baseline: 13.8772x; 1.0762x over previous
//
#include <hip/hip_runtime.h>

#define NN 50000
#define IN_DIM 128
#define HD 96
#define BN_EPS 1e-5f
#define PN_SCALE 20.0f
#define SCAN_NB 196   // ceil(50000/256)

using bf16x8 = __attribute__((ext_vector_type(8))) short;
using f32x4  = __attribute__((ext_vector_type(4))) float;

__device__ __forceinline__ float4 ld4(const float* p) { return *(const float4*)p; }
__device__ __forceinline__ float4 add4(float4 a, float4 b) {
    return make_float4(a.x + b.x, a.y + b.y, a.z + b.z, a.w + b.w);
}

// fp32 -> bf16 round-to-nearest-even (bit trick; no builtin dependency)
__device__ __forceinline__ short bfr(float f) {
    unsigned u = __float_as_uint(f);
    unsigned r = u + 0x7fffu + ((u >> 16) & 1u);
    return (short)(r >> 16);
}
__device__ __forceinline__ bf16x8 cvt8(float4 a, float4 b) {
    bf16x8 r;
    r[0] = bfr(a.x); r[1] = bfr(a.y); r[2] = bfr(a.z); r[3] = bfr(a.w);
    r[4] = bfr(b.x); r[5] = bfr(b.y); r[6] = bfr(b.z); r[7] = bfr(b.w);
    return r;
}

// ---------------- zero stats + CSR counters ----------------
__global__ void zero_kernel(float* stats, int* cnt) {
    int i = blockIdx.x * blockDim.x + threadIdx.x;
    if (i < 1024) stats[i] = 0.0f;
    int j = i - 1024;
    if (j >= 0 && j < NN) cnt[j] = 0;
}

// ---------------- MFMA GEMM: C[N,96] = act(A[N,K]) @ W[96,K]^T + b ----------
// mfma_f32_16x16x32_bf16. 256 threads = 4 waves; wave w owns rows w*16..+15 x
// 96 cols (6 n-tiles, acc 6x f32x4). W converted once/block to bf16 LDS
// (row-major, pitch K+8 -> ~2-way banks); B-frag = 1 ds_read_b128. A-frags
// stream from global (lane: 8 consecutive fp32, rows wave-exclusive -> no
// barriers in K-loop, in-place safe). Layouts (m89-verified C/D):
//   A: row=l&15, k=(l>>4)*8+j | B: col=l&15, same k | C: col=l&15, row=(l>>4)*4+r
// bf16 rounding: RNE; error ~1e-2 on these magnitudes vs 0.1975 threshold.
// Rounds 3-9 lesson: scalar-core GEMM plateaus at 64-80us (LDS latency with
// ~6 waves/CU); matrix cores are the structural escape (no fp32 MFMA -> bf16).
// MODE 0 fuses the edge histogram (4 atomics/thread drain under K-loop).
template<int K, int MODE>
__global__ __launch_bounds__(256) void gemm_mfma(
    const float* A, const float* __restrict__ W, const float* __restrict__ bias,
    float* out, const float* __restrict__ scale, const float* __restrict__ shift,
    float* __restrict__ gsum, float* __restrict__ gsumsq,
    float* __restrict__ gcol, float* __restrict__ growss,
    const int* __restrict__ ei, int* __restrict__ hist_cnt, int E)
{
    constexpr int P   = K + 8;     // bf16 pitch: 16B-aligned rows, spread banks
    constexpr int NS  = K / 32;    // K-steps
    constexpr int KD4 = K / 4;     // dword4 chunks per W row
    __shared__ short Wl[96 * P];

    const int t    = threadIdx.x;
    const int l    = t & 63;
    const int w    = t >> 6;       // wave 0..3
    const int l15  = l & 15;
    const int lh   = l >> 4;       // 0..3
    const int base = blockIdx.x * 64;

    if (MODE == 0) {               // fused histogram: 4 edges/thread
        int e0 = (blockIdx.x * 256 + t) * 4;
        if (e0 + 4 <= E) {
            int4 d4 = *(const int4*)(ei + E + e0);
            atomicAdd(&hist_cnt[d4.x], 1); atomicAdd(&hist_cnt[d4.y], 1);
            atomicAdd(&hist_cnt[d4.z], 1); atomicAdd(&hist_cnt[d4.w], 1);
        } else {
            for (int i = 0; i < 4; ++i) {
                int e = e0 + i;
                if (e < E) atomicAdd(&hist_cnt[ei[E + e]], 1);
            }
        }
    }

    // ---- stage W -> bf16 LDS (once per block) ----
    for (int c = t; c < 96 * KD4; c += 256) {
        int row = c / KD4, kq = c - row * KD4;
        float4 v = ld4(W + (size_t)row * K + kq * 4);
        short4 s;
        s.x = bfr(v.x); s.y = bfr(v.y); s.z = bfr(v.z); s.w = bfr(v.w);
        *(short4*)(Wl + row * P + kq * 4) = s;
    }
    __syncthreads();

    f32x4 acc[6];
#pragma unroll
    for (int n = 0; n < 6; ++n) acc[n] = (f32x4){0.f, 0.f, 0.f, 0.f};

    const int  arow = base + w * 16 + l15;
    const bool aok  = arow < NN;
    const float* Ap = A + (size_t)arow * K + lh * 8;
    const float4 Z4 = make_float4(0.f, 0.f, 0.f, 0.f);

    float4 pa0 = aok ? ld4(Ap)     : Z4;
    float4 pa1 = aok ? ld4(Ap + 4) : Z4;

#pragma unroll
    for (int s = 0; s < NS; ++s) {
        float4 pb0 = Z4, pb1 = Z4;
        if (s + 1 < NS && aok) {               // prefetch next K-step
            pb0 = ld4(Ap + (s + 1) * 32);
            pb1 = ld4(Ap + (s + 1) * 32 + 4);
        }
        float4 q0 = pa0, q1 = pa1;
        if (MODE == 2) {                       // bn+relu on A in fp32
            float4 sc0 = ld4(scale + s * 32 + lh * 8);
            float4 sh0 = ld4(shift + s * 32 + lh * 8);
            float4 sc1 = ld4(scale + s * 32 + lh * 8 + 4);
            float4 sh1 = ld4(shift + s * 32 + lh * 8 + 4);
            q0.x = fmaxf(q0.x * sc0.x + sh0.x, 0.f);
            q0.y = fmaxf(q0.y * sc0.y + sh0.y, 0.f);
            q0.z = fmaxf(q0.z * sc0.z + sh0.z, 0.f);
            q0.w = fmaxf(q0.w * sc0.w + sh0.w, 0.f);
            q1.x = fmaxf(q1.x * sc1.x + sh1.x, 0.f);
            q1.y = fmaxf(q1.y * sc1.y + sh1.y, 0.f);
            q1.z = fmaxf(q1.z * sc1.z + sh1.z, 0.f);
            q1.w = fmaxf(q1.w * sc1.w + sh1.w, 0.f);
        }
        bf16x8 af = cvt8(q0, q1);
        const short* wp = Wl + s * 32 + lh * 8;
#pragma unroll
        for (int n = 0; n < 6; ++n) {
            bf16x8 bf = *(const bf16x8*)(wp + (n * 16 + l15) * P);
            acc[n] = __builtin_amdgcn_mfma_f32_16x16x32_bf16(af, bf, acc[n], 0, 0, 0);
        }
        pa0 = pb0; pa1 = pb1;
    }

    // ---- epilogue: bias + store (C: col=l15, row=lh*4+r within wave tile) ----
    float cv[6][4];
#pragma unroll
    for (int n = 0; n < 6; ++n) {
        float b = bias[n * 16 + l15];
#pragma unroll
        for (int r = 0; r < 4; ++r) cv[n][r] = acc[n][r] + b;
    }
    int crow[4]; bool cok[4];
#pragma unroll
    for (int r = 0; r < 4; ++r) {
        crow[r] = base + w * 16 + lh * 4 + r;
        cok[r]  = crow[r] < NN;
    }
#pragma unroll
    for (int r = 0; r < 4; ++r) {
        if (cok[r]) {
            float* o = out + (size_t)crow[r] * HD + l15;
#pragma unroll
            for (int n = 0; n < 6; ++n) o[n * 16] = cv[n][r];
        }
    }

    if (MODE == 1) {
        float s[6], q[6];
#pragma unroll
        for (int n = 0; n < 6; ++n) {
            s[n] = 0.f; q[n] = 0.f;
#pragma unroll
            for (int r = 0; r < 4; ++r) {
                float v = cok[r] ? cv[n][r] : 0.f;
                s[n] += v; q[n] += v * v;
            }
        }
#pragma unroll
        for (int n = 0; n < 6; ++n) {
            s[n] += __shfl_xor(s[n], 16); s[n] += __shfl_xor(s[n], 32);
            q[n] += __shfl_xor(q[n], 16); q[n] += __shfl_xor(q[n], 32);
        }
        __syncthreads();                       // Wl dead everywhere; overlay
        float* red0 = (float*)Wl;              // [4][96]
        float* red1 = red0 + 384;              // [4][96]
        if (lh == 0) {
#pragma unroll
            for (int n = 0; n < 6; ++n) {
                red0[w * 96 + n * 16 + l15] = s[n];
                red1[w * 96 + n * 16 + l15] = q[n];
            }
        }
        __syncthreads();
        if (t < HD) {
            float S = red0[t] + red0[96 + t] + red0[192 + t] + red0[288 + t];
            float Q = red1[t] + red1[96 + t] + red1[192 + t] + red1[288 + t];
            atomicAdd(&gsum[t], S);
            atomicAdd(&gsumsq[t], Q);
        }
    }

    if (MODE == 2) {
        float s[6];
#pragma unroll
        for (int n = 0; n < 6; ++n) {
            s[n] = 0.f;
#pragma unroll
            for (int r = 0; r < 4; ++r) s[n] += cok[r] ? cv[n][r] : 0.f;
        }
#pragma unroll
        for (int n = 0; n < 6; ++n) {
            s[n] += __shfl_xor(s[n], 16); s[n] += __shfl_xor(s[n], 32);
        }
        float rq[4];
#pragma unroll
        for (int r = 0; r < 4; ++r) {
            float v = 0.f;
#pragma unroll
            for (int n = 0; n < 6; ++n) v = fmaf(cv[n][r], cv[n][r], v);
            v += __shfl_xor(v, 1); v += __shfl_xor(v, 2);
            v += __shfl_xor(v, 4); v += __shfl_xor(v, 8);
            rq[r] = v;
        }
        __syncthreads();                       // Wl dead; overlay
        float* red0 = (float*)Wl;              // [4][96]
        if (lh == 0) {
#pragma unroll
            for (int n = 0; n < 6; ++n) red0[w * 96 + n * 16 + l15] = s[n];
        }
        __syncthreads();
        if (t < HD) {
            float S = red0[t] + red0[96 + t] + red0[192 + t] + red0[288 + t];
            atomicAdd(&gcol[t], S);
        }
        if (l15 == 0) {
#pragma unroll
            for (int r = 0; r < 4; ++r)
                if (cok[r]) growss[crow[r]] = rq[r];
        }
    }
}

// ---------------- CSR build ----------------
__global__ __launch_bounds__(256) void scan_part1(const int* __restrict__ cnt,
                                                  int* __restrict__ bsum) {
    __shared__ int sh[256];
    int i = blockIdx.x * 256 + threadIdx.x;
    int t = threadIdx.x;
    sh[t] = (i < NN) ? cnt[i] : 0;
    __syncthreads();
    for (int off = 128; off > 0; off >>= 1) {
        if (t < off) sh[t] += sh[t + off];
        __syncthreads();
    }
    if (t == 0) bsum[blockIdx.x] = sh[0];
}

__global__ __launch_bounds__(256) void scan_part2(int* __restrict__ bsum) {
    __shared__ int sh[256];
    int t = threadIdx.x;
    int v = (t < SCAN_NB) ? bsum[t] : 0;
    sh[t] = v;
    __syncthreads();
    for (int off = 1; off < 256; off <<= 1) {
        int u = sh[t];
        if (t >= off) u += sh[t - off];
        __syncthreads();
        sh[t] = u;
        __syncthreads();
    }
    if (t < SCAN_NB) bsum[t] = sh[t] - v;    // exclusive block offsets
}

__global__ __launch_bounds__(256) void scan_part3(int* __restrict__ cnt,
                                                  const int* __restrict__ bsum,
                                                  int* __restrict__ rowptr) {
    __shared__ int sh[256];
    int i = blockIdx.x * 256 + threadIdx.x;
    int t = threadIdx.x;
    int v = (i < NN) ? cnt[i] : 0;
    sh[t] = v;
    __syncthreads();
    for (int off = 1; off < 256; off <<= 1) {
        int u = sh[t];
        if (t >= off) u += sh[t - off];
        __syncthreads();
        sh[t] = u;
        __syncthreads();
    }
    int excl = sh[t] - v + bsum[blockIdx.x];
    if (i < NN) { rowptr[i] = excl; cnt[i] = excl; }   // cnt becomes fill cursor
    if (i == NN - 1) rowptr[NN] = excl + v;
}

// fill with dst-range multipass: clusters slot-writes of a row in time so the
// srcs write window per pass (~460 KB) stays L2-resident -> line coalescing.
// (Round-1 A/B: removing the pass clustering raised WRITE_SIZE 40->52.6 MB and
// slowed fill 46.5->55 us despite 2x occupancy -> clustering is load-bearing.)
__global__ __launch_bounds__(256) void fill_kernel(const int* __restrict__ ei,
                                                   int* __restrict__ cursor,
                                                   int* __restrict__ srcs, int E) {
    int t2 = blockIdx.x * 256 + threadIdx.x;
    int e0 = t2 * 2;
    int src[2], dst[2];
#pragma unroll
    for (int i = 0; i < 2; ++i) {
        int e = e0 + i;
        bool ok = e < E;
        dst[i] = ok ? ei[E + e] : -1;
        src[i] = ok ? ei[e] : 0;
    }
    for (int pass = 0; pass < 7; ++pass) {
#pragma unroll
        for (int i = 0; i < 2; ++i) {
            if (dst[i] >= 0 && (dst[i] >> 13) == pass) {
                int slot = atomicAdd(&cursor[dst[i]], 1);
                srcs[slot] = src[i];
            }
        }
    }
}

// -------- gather: z[i] = h0[i] + sum_{e:dst=i} h0[src_e] --------------------
// One 24-lane group owns a full row (24 x float4 = 96 floats). No LDS, no
// __syncthreads: waves retire independently, 8-deep load batches give MLP.
__global__ __launch_bounds__(192) void gather_kernel(
    const float* __restrict__ h0, const int* __restrict__ rowptr,
    const int* __restrict__ srcs, float* __restrict__ z)
{
    const int tid = threadIdx.x;
    const int rl  = tid / 24;          // 0..7 local row
    const int c   = tid - rl * 24;     // 0..23 float4 lane
    const int row = blockIdx.x * 8 + rl;
    if (row >= NN) return;

    const int p0 = rowptr[row];
    const int p1 = rowptr[row + 1];

    float4 acc = ld4(h0 + (size_t)row * HD + c * 4);

    int p = p0;
    for (; p + 8 <= p1; p += 8) {
        int s0 = srcs[p + 0], s1 = srcs[p + 1], s2 = srcs[p + 2], s3 = srcs[p + 3];
        int s4 = srcs[p + 4], s5 = srcs[p + 5], s6 = srcs[p + 6], s7 = srcs[p + 7];
        float4 v0 = ld4(h0 + (size_t)s0 * HD + c * 4);
        float4 v1 = ld4(h0 + (size_t)s1 * HD + c * 4);
        float4 v2 = ld4(h0 + (size_t)s2 * HD + c * 4);
        float4 v3 = ld4(h0 + (size_t)s3 * HD + c * 4);
        float4 v4 = ld4(h0 + (size_t)s4 * HD + c * 4);
        float4 v5 = ld4(h0 + (size_t)s5 * HD + c * 4);
        float4 v6 = ld4(h0 + (size_t)s6 * HD + c * 4);
        float4 v7 = ld4(h0 + (size_t)s7 * HD + c * 4);
        acc = add4(acc, add4(add4(add4(v0, v1), add4(v2, v3)),
                             add4(add4(v4, v5), add4(v6, v7))));
    }
    for (; p + 4 <= p1; p += 4) {
        int s0 = srcs[p + 0], s1 = srcs[p + 1], s2 = srcs[p + 2], s3 = srcs[p + 3];
        float4 v0 = ld4(h0 + (size_t)s0 * HD + c * 4);
        float4 v1 = ld4(h0 + (size_t)s1 * HD + c * 4);
        float4 v2 = ld4(h0 + (size_t)s2 * HD + c * 4);
        float4 v3 = ld4(h0 + (size_t)s3 * HD + c * 4);
        acc = add4(acc, add4(add4(v0, v1), add4(v2, v3)));
    }
    for (; p < p1; ++p)
        acc = add4(acc, ld4(h0 + (size_t)srcs[p] * HD + c * 4));

    *(float4*)(z + (size_t)row * HD + c * 4) = acc;
}

__global__ void bn_finalize_kernel(const float* __restrict__ sum, const float* __restrict__ sumsq,
                                   const float* __restrict__ gamma, const float* __restrict__ beta,
                                   float* __restrict__ scale, float* __restrict__ shift)
{
    int f = threadIdx.x;
    if (f < HD) {
        float mean = sum[f] * (1.0f / NN);
        float var  = fmaxf(sumsq[f] * (1.0f / NN) - mean * mean, 0.0f);
        float rstd = rsqrtf(var + BN_EPS);
        float sc = rstd * gamma[f];
        scale[f] = sc;
        shift[f] = beta[f] - mean * sc;
    }
}

// ---------------- PairNorm: streaming float4, in place ----------------
__global__ __launch_bounds__(256) void pn_kernel(float* l1, const float* __restrict__ colsum,
                                                 const float* __restrict__ rowss)
{
    int idx = blockIdx.x * 256 + threadIdx.x;   // float4 index
    if (idx >= NN * 24) return;
    int row = idx / 24;
    int q = idx - row * 24;
    float rs = rsqrtf(1e-6f + rowss[row]);
    float4 v = ld4(l1 + (size_t)idx * 4);
    float4 cm = ld4(colsum + q * 4);
    v.x = PN_SCALE * v.x * rs - cm.x * (1.0f / NN);
    v.y = PN_SCALE * v.y * rs - cm.y * (1.0f / NN);
    v.z = PN_SCALE * v.z * rs - cm.z * (1.0f / NN);
    v.w = PN_SCALE * v.w * rs - cm.w * (1.0f / NN);
    *(float4*)(l1 + (size_t)idx * 4) = v;
}

extern "C" void kernel_launch(void* const* d_in, const int* in_sizes, int n_in,
                              void* d_out, int out_size, void* d_ws, size_t ws_size,
                              hipStream_t stream) {
    const float* x     = (const float*)d_in[0];
    const int*   ei    = (const int*)d_in[1];
    const float* W0    = (const float*)d_in[2];
    const float* b0    = (const float*)d_in[3];
    const float* W1    = (const float*)d_in[4];
    const float* b1    = (const float*)d_in[5];
    const float* gamma = (const float*)d_in[6];
    const float* beta  = (const float*)d_in[7];
    const float* W2    = (const float*)d_in[8];
    const float* b2    = (const float*)d_in[9];

    float* out_l1 = (float*)d_out;                 // [N,96]: z -> h -> l1 (in place)
    float* out_h0 = out_l1 + (size_t)NN * HD;      // [N,96]: h0 output

    float* stats   = (float*)d_ws;
    float* s_sum   = stats;            // 96
    float* s_sumsq = stats + HD;       // 96
    float* s_col   = stats + 2 * HD;   // 96
    float* s_scale = stats + 288;      // 96
    float* s_shift = stats + 384;      // 96
    float* rowss = stats + 1024;
    int* cnt    = (int*)(rowss + NN);
    int* rowptr = cnt + NN;
    int* bsum   = rowptr + NN + 2;
    int* srcs   = bsum + 256;

    const int E = in_sizes[1] / 2;                 // 800000
    const int GB = (NN + 63) / 64;                 // 782

    zero_kernel<<<(1024 + NN + 255) / 256, 256, 0, stream>>>(stats, cnt);
    // 1) h0 = x @ W0^T + b0 (MFMA), edge histogram fused (4 atomics/thread)
    gemm_mfma<IN_DIM, 0><<<GB, 256, 0, stream>>>(x, W0, b0, out_h0, nullptr, nullptr,
                                                 nullptr, nullptr, nullptr, nullptr,
                                                 ei, cnt, E);
    // 2) CSR build: hierarchical scan -> multipass fill
    scan_part1<<<SCAN_NB, 256, 0, stream>>>(cnt, bsum);
    scan_part2<<<1, 256, 0, stream>>>(bsum);
    scan_part3<<<SCAN_NB, 256, 0, stream>>>(cnt, bsum, rowptr);
    fill_kernel<<<(E / 2 + 255) / 256, 256, 0, stream>>>(ei, cnt, srcs, E);
    // 3) gather: z = h0 + segment_sum(h0[src])
    gather_kernel<<<(NN + 7) / 8, 192, 0, stream>>>(out_h0, rowptr, srcs, out_l1);
    // 4) h = z @ W1^T + b1 (in place, MFMA) + fused BN stats
    gemm_mfma<HD, 1><<<GB, 256, 0, stream>>>(out_l1, W1, b1, out_l1, nullptr, nullptr,
                                             s_sum, s_sumsq, nullptr, nullptr,
                                             nullptr, nullptr, 0);
    bn_finalize_kernel<<<1, 128, 0, stream>>>(s_sum, s_sumsq, gamma, beta, s_scale, s_shift);
    // 5) l1 = relu(bn(h)) @ W2^T + b2 (in place, MFMA) + fused PN stats
    gemm_mfma<HD, 2><<<GB, 256, 0, stream>>>(out_l1, W2, b2, out_l1, s_scale, s_shift,
                                             nullptr, nullptr, s_col, rowss,
                                             nullptr, nullptr, 0);
    // 6) PairNorm finalize (streaming, in place)
    pn_kernel<<<(NN * 24 + 255) / 256, 256, 0, stream>>>(out_l1, s_col, rowss);
}

// Round 11
// 298.514 us; speedup vs baseline: 14.2374x; 1.0260x over previous
//
#include <hip/hip_runtime.h>

#define NN 50000
#define IN_DIM 128
#define HD 96
#define BN_EPS 1e-5f
#define PN_SCALE 20.0f
#define SCAN_NB 196   // ceil(50000/256)

using bf16x8 = __attribute__((ext_vector_type(8))) short;
using f32x4  = __attribute__((ext_vector_type(4))) float;

__device__ __forceinline__ float4 ld4(const float* p) { return *(const float4*)p; }
__device__ __forceinline__ float4 add4(float4 a, float4 b) {
    return make_float4(a.x + b.x, a.y + b.y, a.z + b.z, a.w + b.w);
}

// fp32 -> bf16 round-to-nearest-even (bit trick; no builtin dependency)
__device__ __forceinline__ short bfr(float f) {
    unsigned u = __float_as_uint(f);
    unsigned r = u + 0x7fffu + ((u >> 16) & 1u);
    return (short)(r >> 16);
}
__device__ __forceinline__ bf16x8 cvt8(float4 a, float4 b) {
    bf16x8 r;
    r[0] = bfr(a.x); r[1] = bfr(a.y); r[2] = bfr(a.z); r[3] = bfr(a.w);
    r[4] = bfr(b.x); r[5] = bfr(b.y); r[6] = bfr(b.z); r[7] = bfr(b.w);
    return r;
}

// ---------------- zero stats + CSR counters ----------------
__global__ void zero_kernel(float* stats, int* cnt) {
    int i = blockIdx.x * blockDim.x + threadIdx.x;
    if (i < 1024) stats[i] = 0.0f;
    int j = i - 1024;
    if (j >= 0 && j < NN) cnt[j] = 0;
}

// ---------------- MFMA GEMM: C[N,96] = act(A[N,K]) @ W[96,K]^T + b ----------
// Round-10 structure (mfma_f32_16x16x32_bf16, 4 waves, wave-exclusive rows,
// W->bf16 LDS once/block) with round-11 MLP scheduling: (1) ALL of a lane's
// A-loads issue first (2*NS in flight through staging+barrier), (2) W-stage
// loads clustered into regs then cvt+ds_write (one drain, not 12 chains),
// (3) MODE2 BN+ReLU applied to A regs pre-barrier -> K-loop is pure LDS+MFMA.
// Round-10 PMC: dur ~= bytes/1.2TB/s, all pipes <4% -> outstanding-load-bound
// (~100KB in flight chip-wide; need ~4MB). This gets ~20 loads/thread in air.
// In-place safe: all A loads precede all stores in program order per wave.
// MODE 0 fuses the edge histogram (4 atomics/thread drain under K-loop).
template<int K, int MODE>
__global__ __launch_bounds__(256) void gemm_mfma(
    const float* A, const float* __restrict__ W, const float* __restrict__ bias,
    float* out, const float* __restrict__ scale, const float* __restrict__ shift,
    float* __restrict__ gsum, float* __restrict__ gsumsq,
    float* __restrict__ gcol, float* __restrict__ growss,
    const int* __restrict__ ei, int* __restrict__ hist_cnt, int E)
{
    constexpr int P     = K + 8;   // bf16 pitch: 16B-aligned rows, spread banks
    constexpr int NS    = K / 32;  // K-steps
    constexpr int KD4   = K / 4;   // dword4 chunks per W row
    constexpr int WITER = (96 * KD4) / 256;   // 12 (K=128) / 9 (K=96)
    __shared__ short Wl[96 * P];

    const int t    = threadIdx.x;
    const int l    = t & 63;
    const int w    = t >> 6;       // wave 0..3
    const int l15  = l & 15;
    const int lh   = l >> 4;       // 0..3
    const int base = blockIdx.x * 64;

    const int  arow = base + w * 16 + l15;
    const bool aok  = arow < NN;
    const float* Ap = A + (size_t)arow * K + lh * 8;
    const float4 Z4 = make_float4(0.f, 0.f, 0.f, 0.f);

    // (1) issue ALL A-row loads up front — in flight through staging+barrier
    float4 pa[2 * NS];
#pragma unroll
    for (int s = 0; s < NS; ++s) {
        pa[2 * s]     = aok ? ld4(Ap + s * 32)     : Z4;
        pa[2 * s + 1] = aok ? ld4(Ap + s * 32 + 4) : Z4;
    }

    if (MODE == 0) {               // fused histogram: 4 edges/thread
        int e0 = (blockIdx.x * 256 + t) * 4;
        if (e0 + 4 <= E) {
            int4 d4 = *(const int4*)(ei + E + e0);
            atomicAdd(&hist_cnt[d4.x], 1); atomicAdd(&hist_cnt[d4.y], 1);
            atomicAdd(&hist_cnt[d4.z], 1); atomicAdd(&hist_cnt[d4.w], 1);
        } else {
            for (int i = 0; i < 4; ++i) {
                int e = e0 + i;
                if (e < E) atomicAdd(&hist_cnt[ei[E + e]], 1);
            }
        }
    }

    // (2) W stage: cluster the loads, then convert+write (single vmcnt drain)
    float4 wv[WITER];
#pragma unroll
    for (int i = 0; i < WITER; ++i) {
        int c = t + i * 256;
        int row = c / KD4, kq = c - row * KD4;
        wv[i] = ld4(W + (size_t)row * K + kq * 4);
    }

    // (3) MODE 2: BN+ReLU on A registers before the barrier (A-wait overlaps
    // the still-in-flight W loads); K-loop then touches no global memory.
    if (MODE == 2) {
#pragma unroll
        for (int s = 0; s < NS; ++s) {
            float4 sc0 = ld4(scale + s * 32 + lh * 8);
            float4 sh0 = ld4(shift + s * 32 + lh * 8);
            float4 sc1 = ld4(scale + s * 32 + lh * 8 + 4);
            float4 sh1 = ld4(shift + s * 32 + lh * 8 + 4);
            float4 q0 = pa[2 * s], q1 = pa[2 * s + 1];
            q0.x = fmaxf(q0.x * sc0.x + sh0.x, 0.f);
            q0.y = fmaxf(q0.y * sc0.y + sh0.y, 0.f);
            q0.z = fmaxf(q0.z * sc0.z + sh0.z, 0.f);
            q0.w = fmaxf(q0.w * sc0.w + sh0.w, 0.f);
            q1.x = fmaxf(q1.x * sc1.x + sh1.x, 0.f);
            q1.y = fmaxf(q1.y * sc1.y + sh1.y, 0.f);
            q1.z = fmaxf(q1.z * sc1.z + sh1.z, 0.f);
            q1.w = fmaxf(q1.w * sc1.w + sh1.w, 0.f);
            pa[2 * s] = q0; pa[2 * s + 1] = q1;
        }
    }

#pragma unroll
    for (int i = 0; i < WITER; ++i) {
        int c = t + i * 256;
        int row = c / KD4, kq = c - row * KD4;
        short4 s4v;
        s4v.x = bfr(wv[i].x); s4v.y = bfr(wv[i].y);
        s4v.z = bfr(wv[i].z); s4v.w = bfr(wv[i].w);
        *(short4*)(Wl + row * P + kq * 4) = s4v;
    }
    __syncthreads();

    f32x4 acc[6];
#pragma unroll
    for (int n = 0; n < 6; ++n) acc[n] = (f32x4){0.f, 0.f, 0.f, 0.f};

#pragma unroll
    for (int s = 0; s < NS; ++s) {
        bf16x8 af = cvt8(pa[2 * s], pa[2 * s + 1]);
        const short* wp = Wl + s * 32 + lh * 8;
#pragma unroll
        for (int n = 0; n < 6; ++n) {
            bf16x8 bf = *(const bf16x8*)(wp + (n * 16 + l15) * P);
            acc[n] = __builtin_amdgcn_mfma_f32_16x16x32_bf16(af, bf, acc[n], 0, 0, 0);
        }
    }

    // ---- epilogue: bias + store (C: col=l15, row=lh*4+r within wave tile) ----
    float cv[6][4];
#pragma unroll
    for (int n = 0; n < 6; ++n) {
        float b = bias[n * 16 + l15];
#pragma unroll
        for (int r = 0; r < 4; ++r) cv[n][r] = acc[n][r] + b;
    }
    int crow[4]; bool cok[4];
#pragma unroll
    for (int r = 0; r < 4; ++r) {
        crow[r] = base + w * 16 + lh * 4 + r;
        cok[r]  = crow[r] < NN;
    }
#pragma unroll
    for (int r = 0; r < 4; ++r) {
        if (cok[r]) {
            float* o = out + (size_t)crow[r] * HD + l15;
#pragma unroll
            for (int n = 0; n < 6; ++n) o[n * 16] = cv[n][r];
        }
    }

    if (MODE == 1) {
        float s[6], q[6];
#pragma unroll
        for (int n = 0; n < 6; ++n) {
            s[n] = 0.f; q[n] = 0.f;
#pragma unroll
            for (int r = 0; r < 4; ++r) {
                float v = cok[r] ? cv[n][r] : 0.f;
                s[n] += v; q[n] += v * v;
            }
        }
#pragma unroll
        for (int n = 0; n < 6; ++n) {
            s[n] += __shfl_xor(s[n], 16); s[n] += __shfl_xor(s[n], 32);
            q[n] += __shfl_xor(q[n], 16); q[n] += __shfl_xor(q[n], 32);
        }
        __syncthreads();                       // Wl dead everywhere; overlay
        float* red0 = (float*)Wl;              // [4][96]
        float* red1 = red0 + 384;              // [4][96]
        if (lh == 0) {
#pragma unroll
            for (int n = 0; n < 6; ++n) {
                red0[w * 96 + n * 16 + l15] = s[n];
                red1[w * 96 + n * 16 + l15] = q[n];
            }
        }
        __syncthreads();
        if (t < HD) {
            float S = red0[t] + red0[96 + t] + red0[192 + t] + red0[288 + t];
            float Q = red1[t] + red1[96 + t] + red1[192 + t] + red1[288 + t];
            atomicAdd(&gsum[t], S);
            atomicAdd(&gsumsq[t], Q);
        }
    }

    if (MODE == 2) {
        float s[6];
#pragma unroll
        for (int n = 0; n < 6; ++n) {
            s[n] = 0.f;
#pragma unroll
            for (int r = 0; r < 4; ++r) s[n] += cok[r] ? cv[n][r] : 0.f;
        }
#pragma unroll
        for (int n = 0; n < 6; ++n) {
            s[n] += __shfl_xor(s[n], 16); s[n] += __shfl_xor(s[n], 32);
        }
        float rq[4];
#pragma unroll
        for (int r = 0; r < 4; ++r) {
            float v = 0.f;
#pragma unroll
            for (int n = 0; n < 6; ++n) v = fmaf(cv[n][r], cv[n][r], v);
            v += __shfl_xor(v, 1); v += __shfl_xor(v, 2);
            v += __shfl_xor(v, 4); v += __shfl_xor(v, 8);
            rq[r] = v;
        }
        __syncthreads();                       // Wl dead; overlay
        float* red0 = (float*)Wl;              // [4][96]
        if (lh == 0) {
#pragma unroll
            for (int n = 0; n < 6; ++n) red0[w * 96 + n * 16 + l15] = s[n];
        }
        __syncthreads();
        if (t < HD) {
            float S = red0[t] + red0[96 + t] + red0[192 + t] + red0[288 + t];
            atomicAdd(&gcol[t], S);
        }
        if (l15 == 0) {
#pragma unroll
            for (int r = 0; r < 4; ++r)
                if (cok[r]) growss[crow[r]] = rq[r];
        }
    }
}

// ---------------- CSR build ----------------
__global__ __launch_bounds__(256) void scan_part1(const int* __restrict__ cnt,
                                                  int* __restrict__ bsum) {
    __shared__ int sh[256];
    int i = blockIdx.x * 256 + threadIdx.x;
    int t = threadIdx.x;
    sh[t] = (i < NN) ? cnt[i] : 0;
    __syncthreads();
    for (int off = 128; off > 0; off >>= 1) {
        if (t < off) sh[t] += sh[t + off];
        __syncthreads();
    }
    if (t == 0) bsum[blockIdx.x] = sh[0];
}

__global__ __launch_bounds__(256) void scan_part2(int* __restrict__ bsum) {
    __shared__ int sh[256];
    int t = threadIdx.x;
    int v = (t < SCAN_NB) ? bsum[t] : 0;
    sh[t] = v;
    __syncthreads();
    for (int off = 1; off < 256; off <<= 1) {
        int u = sh[t];
        if (t >= off) u += sh[t - off];
        __syncthreads();
        sh[t] = u;
        __syncthreads();
    }
    if (t < SCAN_NB) bsum[t] = sh[t] - v;    // exclusive block offsets
}

__global__ __launch_bounds__(256) void scan_part3(int* __restrict__ cnt,
                                                  const int* __restrict__ bsum,
                                                  int* __restrict__ rowptr) {
    __shared__ int sh[256];
    int i = blockIdx.x * 256 + threadIdx.x;
    int t = threadIdx.x;
    int v = (i < NN) ? cnt[i] : 0;
    sh[t] = v;
    __syncthreads();
    for (int off = 1; off < 256; off <<= 1) {
        int u = sh[t];
        if (t >= off) u += sh[t - off];
        __syncthreads();
        sh[t] = u;
        __syncthreads();
    }
    int excl = sh[t] - v + bsum[blockIdx.x];
    if (i < NN) { rowptr[i] = excl; cnt[i] = excl; }   // cnt becomes fill cursor
    if (i == NN - 1) rowptr[NN] = excl + v;
}

// fill with dst-range multipass: clusters slot-writes of a row in time so the
// srcs write window per pass (~460 KB) stays L2-resident -> line coalescing.
// (Round-1 A/B: removing the pass clustering raised WRITE_SIZE 40->52.6 MB and
// slowed fill 46.5->55 us despite 2x occupancy -> clustering is load-bearing.)
__global__ __launch_bounds__(256) void fill_kernel(const int* __restrict__ ei,
                                                   int* __restrict__ cursor,
                                                   int* __restrict__ srcs, int E) {
    int t2 = blockIdx.x * 256 + threadIdx.x;
    int e0 = t2 * 2;
    int src[2], dst[2];
#pragma unroll
    for (int i = 0; i < 2; ++i) {
        int e = e0 + i;
        bool ok = e < E;
        dst[i] = ok ? ei[E + e] : -1;
        src[i] = ok ? ei[e] : 0;
    }
    for (int pass = 0; pass < 7; ++pass) {
#pragma unroll
        for (int i = 0; i < 2; ++i) {
            if (dst[i] >= 0 && (dst[i] >> 13) == pass) {
                int slot = atomicAdd(&cursor[dst[i]], 1);
                srcs[slot] = src[i];
            }
        }
    }
}

// -------- gather: z[i] = h0[i] + sum_{e:dst=i} h0[src_e] --------------------
// One 24-lane group owns a full row (24 x float4 = 96 floats). No LDS, no
// __syncthreads: waves retire independently, 8-deep load batches give MLP.
__global__ __launch_bounds__(192) void gather_kernel(
    const float* __restrict__ h0, const int* __restrict__ rowptr,
    const int* __restrict__ srcs, float* __restrict__ z)
{
    const int tid = threadIdx.x;
    const int rl  = tid / 24;          // 0..7 local row
    const int c   = tid - rl * 24;     // 0..23 float4 lane
    const int row = blockIdx.x * 8 + rl;
    if (row >= NN) return;

    const int p0 = rowptr[row];
    const int p1 = rowptr[row + 1];

    float4 acc = ld4(h0 + (size_t)row * HD + c * 4);

    int p = p0;
    for (; p + 8 <= p1; p += 8) {
        int s0 = srcs[p + 0], s1 = srcs[p + 1], s2 = srcs[p + 2], s3 = srcs[p + 3];
        int s4 = srcs[p + 4], s5 = srcs[p + 5], s6 = srcs[p + 6], s7 = srcs[p + 7];
        float4 v0 = ld4(h0 + (size_t)s0 * HD + c * 4);
        float4 v1 = ld4(h0 + (size_t)s1 * HD + c * 4);
        float4 v2 = ld4(h0 + (size_t)s2 * HD + c * 4);
        float4 v3 = ld4(h0 + (size_t)s3 * HD + c * 4);
        float4 v4 = ld4(h0 + (size_t)s4 * HD + c * 4);
        float4 v5 = ld4(h0 + (size_t)s5 * HD + c * 4);
        float4 v6 = ld4(h0 + (size_t)s6 * HD + c * 4);
        float4 v7 = ld4(h0 + (size_t)s7 * HD + c * 4);
        acc = add4(acc, add4(add4(add4(v0, v1), add4(v2, v3)),
                             add4(add4(v4, v5), add4(v6, v7))));
    }
    for (; p + 4 <= p1; p += 4) {
        int s0 = srcs[p + 0], s1 = srcs[p + 1], s2 = srcs[p + 2], s3 = srcs[p + 3];
        float4 v0 = ld4(h0 + (size_t)s0 * HD + c * 4);
        float4 v1 = ld4(h0 + (size_t)s1 * HD + c * 4);
        float4 v2 = ld4(h0 + (size_t)s2 * HD + c * 4);
        float4 v3 = ld4(h0 + (size_t)s3 * HD + c * 4);
        acc = add4(acc, add4(add4(v0, v1), add4(v2, v3)));
    }
    for (; p < p1; ++p)
        acc = add4(acc, ld4(h0 + (size_t)srcs[p] * HD + c * 4));

    *(float4*)(z + (size_t)row * HD + c * 4) = acc;
}

__global__ void bn_finalize_kernel(const float* __restrict__ sum, const float* __restrict__ sumsq,
                                   const float* __restrict__ gamma, const float* __restrict__ beta,
                                   float* __restrict__ scale, float* __restrict__ shift)
{
    int f = threadIdx.x;
    if (f < HD) {
        float mean = sum[f] * (1.0f / NN);
        float var  = fmaxf(sumsq[f] * (1.0f / NN) - mean * mean, 0.0f);
        float rstd = rsqrtf(var + BN_EPS);
        float sc = rstd * gamma[f];
        scale[f] = sc;
        shift[f] = beta[f] - mean * sc;
    }
}

// ---------------- PairNorm: streaming float4, in place ----------------
__global__ __launch_bounds__(256) void pn_kernel(float* l1, const float* __restrict__ colsum,
                                                 const float* __restrict__ rowss)
{
    int idx = blockIdx.x * 256 + threadIdx.x;   // float4 index
    if (idx >= NN * 24) return;
    int row = idx / 24;
    int q = idx - row * 24;
    float rs = rsqrtf(1e-6f + rowss[row]);
    float4 v = ld4(l1 + (size_t)idx * 4);
    float4 cm = ld4(colsum + q * 4);
    v.x = PN_SCALE * v.x * rs - cm.x * (1.0f / NN);
    v.y = PN_SCALE * v.y * rs - cm.y * (1.0f / NN);
    v.z = PN_SCALE * v.z * rs - cm.z * (1.0f / NN);
    v.w = PN_SCALE * v.w * rs - cm.w * (1.0f / NN);
    *(float4*)(l1 + (size_t)idx * 4) = v;
}

extern "C" void kernel_launch(void* const* d_in, const int* in_sizes, int n_in,
                              void* d_out, int out_size, void* d_ws, size_t ws_size,
                              hipStream_t stream) {
    const float* x     = (const float*)d_in[0];
    const int*   ei    = (const int*)d_in[1];
    const float* W0    = (const float*)d_in[2];
    const float* b0    = (const float*)d_in[3];
    const float* W1    = (const float*)d_in[4];
    const float* b1    = (const float*)d_in[5];
    const float* gamma = (const float*)d_in[6];
    const float* beta  = (const float*)d_in[7];
    const float* W2    = (const float*)d_in[8];
    const float* b2    = (const float*)d_in[9];

    float* out_l1 = (float*)d_out;                 // [N,96]: z -> h -> l1 (in place)
    float* out_h0 = out_l1 + (size_t)NN * HD;      // [N,96]: h0 output

    float* stats   = (float*)d_ws;
    float* s_sum   = stats;            // 96
    float* s_sumsq = stats + HD;       // 96
    float* s_col   = stats + 2 * HD;   // 96
    float* s_scale = stats + 288;      // 96
    float* s_shift = stats + 384;      // 96
    float* rowss = stats + 1024;
    int* cnt    = (int*)(rowss + NN);
    int* rowptr = cnt + NN;
    int* bsum   = rowptr + NN + 2;
    int* srcs   = bsum + 256;

    const int E = in_sizes[1] / 2;                 // 800000
    const int GB = (NN + 63) / 64;                 // 782

    zero_kernel<<<(1024 + NN + 255) / 256, 256, 0, stream>>>(stats, cnt);
    // 1) h0 = x @ W0^T + b0 (MFMA), edge histogram fused (4 atomics/thread)
    gemm_mfma<IN_DIM, 0><<<GB, 256, 0, stream>>>(x, W0, b0, out_h0, nullptr, nullptr,
                                                 nullptr, nullptr, nullptr, nullptr,
                                                 ei, cnt, E);
    // 2) CSR build: hierarchical scan -> multipass fill
    scan_part1<<<SCAN_NB, 256, 0, stream>>>(cnt, bsum);
    scan_part2<<<1, 256, 0, stream>>>(bsum);
    scan_part3<<<SCAN_NB, 256, 0, stream>>>(cnt, bsum, rowptr);
    fill_kernel<<<(E / 2 + 255) / 256, 256, 0, stream>>>(ei, cnt, srcs, E);
    // 3) gather: z = h0 + segment_sum(h0[src])
    gather_kernel<<<(NN + 7) / 8, 192, 0, stream>>>(out_h0, rowptr, srcs, out_l1);
    // 4) h = z @ W1^T + b1 (in place, MFMA) + fused BN stats
    gemm_mfma<HD, 1><<<GB, 256, 0, stream>>>(out_l1, W1, b1, out_l1, nullptr, nullptr,
                                             s_sum, s_sumsq, nullptr, nullptr,
                                             nullptr, nullptr, 0);
    bn_finalize_kernel<<<1, 128, 0, stream>>>(s_sum, s_sumsq, gamma, beta, s_scale, s_shift);
    // 5) l1 = relu(bn(h)) @ W2^T + b2 (in place, MFMA) + fused PN stats
    gemm_mfma<HD, 2><<<GB, 256, 0, stream>>>(out_l1, W2, b2, out_l1, s_scale, s_shift,
                                             nullptr, nullptr, s_col, rowss,
                                             nullptr, nullptr, 0);
    // 6) PairNorm finalize (streaming, in place)
    pn_kernel<<<(NN * 24 + 255) / 256, 256, 0, stream>>>(out_l1, s_col, rowss);
}

// Round 14
// 297.021 us; speedup vs baseline: 14.3090x; 1.0050x over previous
//
#include <hip/hip_runtime.h>

#define NN 50000
#define IN_DIM 128
#define HD 96
#define BN_EPS 1e-5f
#define PN_SCALE 20.0f
#define SCAN_NB 196   // ceil(50000/256)

using bf16x8 = __attribute__((ext_vector_type(8))) short;
using f32x4  = __attribute__((ext_vector_type(4))) float;

__device__ __forceinline__ float4 ld4(const float* p) { return *(const float4*)p; }
__device__ __forceinline__ float4 add4(float4 a, float4 b) {
    return make_float4(a.x + b.x, a.y + b.y, a.z + b.z, a.w + b.w);
}

// fp32 -> bf16 round-to-nearest-even (bit trick; no builtin dependency)
__device__ __forceinline__ short bfr(float f) {
    unsigned u = __float_as_uint(f);
    unsigned r = u + 0x7fffu + ((u >> 16) & 1u);
    return (short)(r >> 16);
}
__device__ __forceinline__ bf16x8 cvt8(float4 a, float4 b) {
    bf16x8 r;
    r[0] = bfr(a.x); r[1] = bfr(a.y); r[2] = bfr(a.z); r[3] = bfr(a.w);
    r[4] = bfr(b.x); r[5] = bfr(b.y); r[6] = bfr(b.z); r[7] = bfr(b.w);
    return r;
}

// ---------------- zero stats + CSR counters ----------------
__global__ void zero_kernel(float* stats, int* cnt) {
    int i = blockIdx.x * blockDim.x + threadIdx.x;
    if (i < 1024) stats[i] = 0.0f;
    int j = i - 1024;
    if (j >= 0 && j < NN) cnt[j] = 0;
}

// ---------------- MFMA GEMM: C[N,96] = act(A[N,K]) @ W[96,K]^T + b ----------
// Round-11 postmortem: VGPR_Count=56 -> the allocator rematerialized the load
// cluster away (it targeted max occupancy the 782-block grid can't use), so
// loads issued serially and BW stuck at 1.25 TB/s. Fix (launch-bounds-free,
// hedging the round-12/13 container failures): pad Wl to 41216 B so LDS caps
// occupancy at 3 blocks/CU == what the grid provides anyway; the backend's
// LDS-derived occupancy target then relaxes the VGPR budget to ~170 so the
// ~20 clustered loads/thread stay live. Staging: all A loads -> all W loads
// (-> sc/sh for MODE2), convert A early (frees 32 VGPR), W cvt+ds_write,
// barrier, pure LDS+MFMA K-loop.
// Layouts (m89-verified): A row=l&15,k=(l>>4)*8+j | B col=l&15 | C col=l&15,
// row=(l>>4)*4+r. In-place safe: all A loads precede all stores per wave.
// MODE 0 fuses the edge histogram (4 atomics/thread drain under staging).
template<int K, int MODE>
__global__ __launch_bounds__(256) void gemm_mfma(
    const float* A, const float* __restrict__ W, const float* __restrict__ bias,
    float* out, const float* __restrict__ scale, const float* __restrict__ shift,
    float* __restrict__ gsum, float* __restrict__ gsumsq,
    float* __restrict__ gcol, float* __restrict__ growss,
    const int* __restrict__ ei, int* __restrict__ hist_cnt, int E)
{
    constexpr int P     = K + 8;   // bf16 pitch: 16B-aligned rows, spread banks
    constexpr int NS    = K / 32;  // K-steps
    constexpr int KD4   = K / 4;   // dword4 chunks per W row
    constexpr int WITER = (96 * KD4) / 256;   // 12 (K=128) / 9 (K=96)
    constexpr int WL_SH  = 96 * P;            // shorts actually used
    constexpr int WL_TOT = (20608 > WL_SH) ? 20608 : WL_SH;  // 41216 B ->
    __shared__ short Wl[WL_TOT];   // LDS caps occupancy at 3 blocks/CU (= grid)

    const int t    = threadIdx.x;
    const int l    = t & 63;
    const int w    = t >> 6;       // wave 0..3
    const int l15  = l & 15;
    const int lh   = l >> 4;       // 0..3
    const int base = blockIdx.x * 64;

    const int  arow = base + w * 16 + l15;
    const bool aok  = arow < NN;
    const float* Ap = A + (size_t)arow * K + lh * 8;
    const float4 Z4 = make_float4(0.f, 0.f, 0.f, 0.f);

    // ---- cluster ALL global loads up front (waitcnt ladder drains in order) --
    float4 pa[2 * NS];
#pragma unroll
    for (int s = 0; s < NS; ++s) {
        pa[2 * s]     = aok ? ld4(Ap + s * 32)     : Z4;
        pa[2 * s + 1] = aok ? ld4(Ap + s * 32 + 4) : Z4;
    }
    float4 wv[WITER];
#pragma unroll
    for (int i = 0; i < WITER; ++i) {
        int c = t + i * 256;
        int row = c / KD4, kq = c - row * KD4;
        wv[i] = ld4(W + (size_t)row * K + kq * 4);
    }
    float4 scv[2 * NS], shv[2 * NS];
    if (MODE == 2) {
#pragma unroll
        for (int s = 0; s < 2 * NS; ++s) {
            scv[s] = ld4(scale + (s >> 1) * 32 + lh * 8 + (s & 1) * 4);
            shv[s] = ld4(shift + (s >> 1) * 32 + lh * 8 + (s & 1) * 4);
        }
    }

    if (MODE == 0) {               // fused histogram: 4 edges/thread
        int e0 = (blockIdx.x * 256 + t) * 4;
        if (e0 + 4 <= E) {
            int4 d4 = *(const int4*)(ei + E + e0);
            atomicAdd(&hist_cnt[d4.x], 1); atomicAdd(&hist_cnt[d4.y], 1);
            atomicAdd(&hist_cnt[d4.z], 1); atomicAdd(&hist_cnt[d4.w], 1);
        } else {
            for (int i = 0; i < 4; ++i) {
                int e = e0 + i;
                if (e < E) atomicAdd(&hist_cnt[ei[E + e]], 1);
            }
        }
    }

    // ---- convert A early (waits only on A loads; frees 2*NS float4s) ----
    bf16x8 af[NS];
#pragma unroll
    for (int s = 0; s < NS; ++s) {
        float4 q0 = pa[2 * s], q1 = pa[2 * s + 1];
        if (MODE == 2) {
            float4 sc0 = scv[2 * s], sh0 = shv[2 * s];
            float4 sc1 = scv[2 * s + 1], sh1 = shv[2 * s + 1];
            q0.x = fmaxf(q0.x * sc0.x + sh0.x, 0.f);
            q0.y = fmaxf(q0.y * sc0.y + sh0.y, 0.f);
            q0.z = fmaxf(q0.z * sc0.z + sh0.z, 0.f);
            q0.w = fmaxf(q0.w * sc0.w + sh0.w, 0.f);
            q1.x = fmaxf(q1.x * sc1.x + sh1.x, 0.f);
            q1.y = fmaxf(q1.y * sc1.y + sh1.y, 0.f);
            q1.z = fmaxf(q1.z * sc1.z + sh1.z, 0.f);
            q1.w = fmaxf(q1.w * sc1.w + sh1.w, 0.f);
        }
        af[s] = cvt8(q0, q1);
    }

    // ---- convert + stage W -> bf16 LDS ----
#pragma unroll
    for (int i = 0; i < WITER; ++i) {
        int c = t + i * 256;
        int row = c / KD4, kq = c - row * KD4;
        short4 s4v;
        s4v.x = bfr(wv[i].x); s4v.y = bfr(wv[i].y);
        s4v.z = bfr(wv[i].z); s4v.w = bfr(wv[i].w);
        *(short4*)(Wl + row * P + kq * 4) = s4v;
    }
    __syncthreads();

    f32x4 acc[6];
#pragma unroll
    for (int n = 0; n < 6; ++n) acc[n] = (f32x4){0.f, 0.f, 0.f, 0.f};

#pragma unroll
    for (int s = 0; s < NS; ++s) {
        const short* wp = Wl + s * 32 + lh * 8;
#pragma unroll
        for (int n = 0; n < 6; ++n) {
            bf16x8 bf = *(const bf16x8*)(wp + (n * 16 + l15) * P);
            acc[n] = __builtin_amdgcn_mfma_f32_16x16x32_bf16(af[s], bf, acc[n], 0, 0, 0);
        }
    }

    // ---- epilogue: bias + store (C: col=l15, row=lh*4+r within wave tile) ----
    float cv[6][4];
#pragma unroll
    for (int n = 0; n < 6; ++n) {
        float b = bias[n * 16 + l15];
#pragma unroll
        for (int r = 0; r < 4; ++r) cv[n][r] = acc[n][r] + b;
    }
    int crow[4]; bool cok[4];
#pragma unroll
    for (int r = 0; r < 4; ++r) {
        crow[r] = base + w * 16 + lh * 4 + r;
        cok[r]  = crow[r] < NN;
    }
#pragma unroll
    for (int r = 0; r < 4; ++r) {
        if (cok[r]) {
            float* o = out + (size_t)crow[r] * HD + l15;
#pragma unroll
            for (int n = 0; n < 6; ++n) o[n * 16] = cv[n][r];
        }
    }

    if (MODE == 1) {
        float s[6], q[6];
#pragma unroll
        for (int n = 0; n < 6; ++n) {
            s[n] = 0.f; q[n] = 0.f;
#pragma unroll
            for (int r = 0; r < 4; ++r) {
                float v = cok[r] ? cv[n][r] : 0.f;
                s[n] += v; q[n] += v * v;
            }
        }
#pragma unroll
        for (int n = 0; n < 6; ++n) {
            s[n] += __shfl_xor(s[n], 16); s[n] += __shfl_xor(s[n], 32);
            q[n] += __shfl_xor(q[n], 16); q[n] += __shfl_xor(q[n], 32);
        }
        __syncthreads();                       // Wl dead everywhere; overlay
        float* red0 = (float*)Wl;              // [4][96]
        float* red1 = red0 + 384;              // [4][96]
        if (lh == 0) {
#pragma unroll
            for (int n = 0; n < 6; ++n) {
                red0[w * 96 + n * 16 + l15] = s[n];
                red1[w * 96 + n * 16 + l15] = q[n];
            }
        }
        __syncthreads();
        if (t < HD) {
            float S = red0[t] + red0[96 + t] + red0[192 + t] + red0[288 + t];
            float Q = red1[t] + red1[96 + t] + red1[192 + t] + red1[288 + t];
            atomicAdd(&gsum[t], S);
            atomicAdd(&gsumsq[t], Q);
        }
    }

    if (MODE == 2) {
        float s[6];
#pragma unroll
        for (int n = 0; n < 6; ++n) {
            s[n] = 0.f;
#pragma unroll
            for (int r = 0; r < 4; ++r) s[n] += cok[r] ? cv[n][r] : 0.f;
        }
#pragma unroll
        for (int n = 0; n < 6; ++n) {
            s[n] += __shfl_xor(s[n], 16); s[n] += __shfl_xor(s[n], 32);
        }
        float rq[4];
#pragma unroll
        for (int r = 0; r < 4; ++r) {
            float v = 0.f;
#pragma unroll
            for (int n = 0; n < 6; ++n) v = fmaf(cv[n][r], cv[n][r], v);
            v += __shfl_xor(v, 1); v += __shfl_xor(v, 2);
            v += __shfl_xor(v, 4); v += __shfl_xor(v, 8);
            rq[r] = v;
        }
        __syncthreads();                       // Wl dead; overlay
        float* red0 = (float*)Wl;              // [4][96]
        if (lh == 0) {
#pragma unroll
            for (int n = 0; n < 6; ++n) red0[w * 96 + n * 16 + l15] = s[n];
        }
        __syncthreads();
        if (t < HD) {
            float S = red0[t] + red0[96 + t] + red0[192 + t] + red0[288 + t];
            atomicAdd(&gcol[t], S);
        }
        if (l15 == 0) {
#pragma unroll
            for (int r = 0; r < 4; ++r)
                if (cok[r]) growss[crow[r]] = rq[r];
        }
    }
}

// ---------------- CSR build ----------------
__global__ __launch_bounds__(256) void scan_part1(const int* __restrict__ cnt,
                                                  int* __restrict__ bsum) {
    __shared__ int sh[256];
    int i = blockIdx.x * 256 + threadIdx.x;
    int t = threadIdx.x;
    sh[t] = (i < NN) ? cnt[i] : 0;
    __syncthreads();
    for (int off = 128; off > 0; off >>= 1) {
        if (t < off) sh[t] += sh[t + off];
        __syncthreads();
    }
    if (t == 0) bsum[blockIdx.x] = sh[0];
}

__global__ __launch_bounds__(256) void scan_part2(int* __restrict__ bsum) {
    __shared__ int sh[256];
    int t = threadIdx.x;
    int v = (t < SCAN_NB) ? bsum[t] : 0;
    sh[t] = v;
    __syncthreads();
    for (int off = 1; off < 256; off <<= 1) {
        int u = sh[t];
        if (t >= off) u += sh[t - off];
        __syncthreads();
        sh[t] = u;
        __syncthreads();
    }
    if (t < SCAN_NB) bsum[t] = sh[t] - v;    // exclusive block offsets
}

__global__ __launch_bounds__(256) void scan_part3(int* __restrict__ cnt,
                                                  const int* __restrict__ bsum,
                                                  int* __restrict__ rowptr) {
    __shared__ int sh[256];
    int i = blockIdx.x * 256 + threadIdx.x;
    int t = threadIdx.x;
    int v = (i < NN) ? cnt[i] : 0;
    sh[t] = v;
    __syncthreads();
    for (int off = 1; off < 256; off <<= 1) {
        int u = sh[t];
        if (t >= off) u += sh[t - off];
        __syncthreads();
        sh[t] = u;
        __syncthreads();
    }
    int excl = sh[t] - v + bsum[blockIdx.x];
    if (i < NN) { rowptr[i] = excl; cnt[i] = excl; }   // cnt becomes fill cursor
    if (i == NN - 1) rowptr[NN] = excl + v;
}

// fill with dst-range multipass: clusters slot-writes of a row in time so the
// srcs write window per pass (~460 KB) stays L2-resident -> line coalescing.
// (Round-1 A/B: removing the pass clustering raised WRITE_SIZE 40->52.6 MB and
// slowed fill 46.5->55 us despite 2x occupancy -> clustering is load-bearing.)
__global__ __launch_bounds__(256) void fill_kernel(const int* __restrict__ ei,
                                                   int* __restrict__ cursor,
                                                   int* __restrict__ srcs, int E) {
    int t2 = blockIdx.x * 256 + threadIdx.x;
    int e0 = t2 * 2;
    int src[2], dst[2];
#pragma unroll
    for (int i = 0; i < 2; ++i) {
        int e = e0 + i;
        bool ok = e < E;
        dst[i] = ok ? ei[E + e] : -1;
        src[i] = ok ? ei[e] : 0;
    }
    for (int pass = 0; pass < 7; ++pass) {
#pragma unroll
        for (int i = 0; i < 2; ++i) {
            if (dst[i] >= 0 && (dst[i] >> 13) == pass) {
                int slot = atomicAdd(&cursor[dst[i]], 1);
                srcs[slot] = src[i];
            }
        }
    }
}

// -------- gather: z[i] = h0[i] + sum_{e:dst=i} h0[src_e] --------------------
// One 24-lane group owns a full row (24 x float4 = 96 floats). No LDS, no
// __syncthreads: waves retire independently, 8-deep load batches give MLP.
__global__ __launch_bounds__(192) void gather_kernel(
    const float* __restrict__ h0, const int* __restrict__ rowptr,
    const int* __restrict__ srcs, float* __restrict__ z)
{
    const int tid = threadIdx.x;
    const int rl  = tid / 24;          // 0..7 local row
    const int c   = tid - rl * 24;     // 0..23 float4 lane
    const int row = blockIdx.x * 8 + rl;
    if (row >= NN) return;

    const int p0 = rowptr[row];
    const int p1 = rowptr[row + 1];

    float4 acc = ld4(h0 + (size_t)row * HD + c * 4);

    int p = p0;
    for (; p + 8 <= p1; p += 8) {
        int s0 = srcs[p + 0], s1 = srcs[p + 1], s2 = srcs[p + 2], s3 = srcs[p + 3];
        int s4 = srcs[p + 4], s5 = srcs[p + 5], s6 = srcs[p + 6], s7 = srcs[p + 7];
        float4 v0 = ld4(h0 + (size_t)s0 * HD + c * 4);
        float4 v1 = ld4(h0 + (size_t)s1 * HD + c * 4);
        float4 v2 = ld4(h0 + (size_t)s2 * HD + c * 4);
        float4 v3 = ld4(h0 + (size_t)s3 * HD + c * 4);
        float4 v4 = ld4(h0 + (size_t)s4 * HD + c * 4);
        float4 v5 = ld4(h0 + (size_t)s5 * HD + c * 4);
        float4 v6 = ld4(h0 + (size_t)s6 * HD + c * 4);
        float4 v7 = ld4(h0 + (size_t)s7 * HD + c * 4);
        acc = add4(acc, add4(add4(add4(v0, v1), add4(v2, v3)),
                             add4(add4(v4, v5), add4(v6, v7))));
    }
    for (; p + 4 <= p1; p += 4) {
        int s0 = srcs[p + 0], s1 = srcs[p + 1], s2 = srcs[p + 2], s3 = srcs[p + 3];
        float4 v0 = ld4(h0 + (size_t)s0 * HD + c * 4);
        float4 v1 = ld4(h0 + (size_t)s1 * HD + c * 4);
        float4 v2 = ld4(h0 + (size_t)s2 * HD + c * 4);
        float4 v3 = ld4(h0 + (size_t)s3 * HD + c * 4);
        acc = add4(acc, add4(add4(v0, v1), add4(v2, v3)));
    }
    for (; p < p1; ++p)
        acc = add4(acc, ld4(h0 + (size_t)srcs[p] * HD + c * 4));

    *(float4*)(z + (size_t)row * HD + c * 4) = acc;
}

__global__ void bn_finalize_kernel(const float* __restrict__ sum, const float* __restrict__ sumsq,
                                   const float* __restrict__ gamma, const float* __restrict__ beta,
                                   float* __restrict__ scale, float* __restrict__ shift)
{
    int f = threadIdx.x;
    if (f < HD) {
        float mean = sum[f] * (1.0f / NN);
        float var  = fmaxf(sumsq[f] * (1.0f / NN) - mean * mean, 0.0f);
        float rstd = rsqrtf(var + BN_EPS);
        float sc = rstd * gamma[f];
        scale[f] = sc;
        shift[f] = beta[f] - mean * sc;
    }
}

// ---------------- PairNorm: streaming float4, in place ----------------
__global__ __launch_bounds__(256) void pn_kernel(float* l1, const float* __restrict__ colsum,
                                                 const float* __restrict__ rowss)
{
    int idx = blockIdx.x * 256 + threadIdx.x;   // float4 index
    if (idx >= NN * 24) return;
    int row = idx / 24;
    int q = idx - row * 24;
    float rs = rsqrtf(1e-6f + rowss[row]);
    float4 v = ld4(l1 + (size_t)idx * 4);
    float4 cm = ld4(colsum + q * 4);
    v.x = PN_SCALE * v.x * rs - cm.x * (1.0f / NN);
    v.y = PN_SCALE * v.y * rs - cm.y * (1.0f / NN);
    v.z = PN_SCALE * v.z * rs - cm.z * (1.0f / NN);
    v.w = PN_SCALE * v.w * rs - cm.w * (1.0f / NN);
    *(float4*)(l1 + (size_t)idx * 4) = v;
}

extern "C" void kernel_launch(void* const* d_in, const int* in_sizes, int n_in,
                              void* d_out, int out_size, void* d_ws, size_t ws_size,
                              hipStream_t stream) {
    const float* x     = (const float*)d_in[0];
    const int*   ei    = (const int*)d_in[1];
    const float* W0    = (const float*)d_in[2];
    const float* b0    = (const float*)d_in[3];
    const float* W1    = (const float*)d_in[4];
    const float* b1    = (const float*)d_in[5];
    const float* gamma = (const float*)d_in[6];
    const float* beta  = (const float*)d_in[7];
    const float* W2    = (const float*)d_in[8];
    const float* b2    = (const float*)d_in[9];

    float* out_l1 = (float*)d_out;                 // [N,96]: z -> h -> l1 (in place)
    float* out_h0 = out_l1 + (size_t)NN * HD;      // [N,96]: h0 output

    float* stats   = (float*)d_ws;
    float* s_sum   = stats;            // 96
    float* s_sumsq = stats + HD;       // 96
    float* s_col   = stats + 2 * HD;   // 96
    float* s_scale = stats + 288;      // 96
    float* s_shift = stats + 384;      // 96
    float* rowss = stats + 1024;
    int* cnt    = (int*)(rowss + NN);
    int* rowptr = cnt + NN;
    int* bsum   = rowptr + NN + 2;
    int* srcs   = bsum + 256;

    const int E = in_sizes[1] / 2;                 // 800000
    const int GB = (NN + 63) / 64;                 // 782

    zero_kernel<<<(1024 + NN + 255) / 256, 256, 0, stream>>>(stats, cnt);
    // 1) h0 = x @ W0^T + b0 (MFMA), edge histogram fused (4 atomics/thread)
    gemm_mfma<IN_DIM, 0><<<GB, 256, 0, stream>>>(x, W0, b0, out_h0, nullptr, nullptr,
                                                 nullptr, nullptr, nullptr, nullptr,
                                                 ei, cnt, E);
    // 2) CSR build: hierarchical scan -> multipass fill
    scan_part1<<<SCAN_NB, 256, 0, stream>>>(cnt, bsum);
    scan_part2<<<1, 256, 0, stream>>>(bsum);
    scan_part3<<<SCAN_NB, 256, 0, stream>>>(cnt, bsum, rowptr);
    fill_kernel<<<(E / 2 + 255) / 256, 256, 0, stream>>>(ei, cnt, srcs, E);
    // 3) gather: z = h0 + segment_sum(h0[src])
    gather_kernel<<<(NN + 7) / 8, 192, 0, stream>>>(out_h0, rowptr, srcs, out_l1);
    // 4) h = z @ W1^T + b1 (in place, MFMA) + fused BN stats
    gemm_mfma<HD, 1><<<GB, 256, 0, stream>>>(out_l1, W1, b1, out_l1, nullptr, nullptr,
                                             s_sum, s_sumsq, nullptr, nullptr,
                                             nullptr, nullptr, 0);
    bn_finalize_kernel<<<1, 128, 0, stream>>>(s_sum, s_sumsq, gamma, beta, s_scale, s_shift);
    // 5) l1 = relu(bn(h)) @ W2^T + b2 (in place, MFMA) + fused PN stats
    gemm_mfma<HD, 2><<<GB, 256, 0, stream>>>(out_l1, W2, b2, out_l1, s_scale, s_shift,
                                             nullptr, nullptr, s_col, rowss,
                                             nullptr, nullptr, 0);
    // 6) PairNorm finalize (streaming, in place)
    pn_kernel<<<(NN * 24 + 255) / 256, 256, 0, stream>>>(out_l1, s_col, rowss);
}

// Round 15
// 292.386 us; speedup vs baseline: 14.5358x; 1.0159x over previous
//
#include <hip/hip_runtime.h>

#define NN 50000
#define IN_DIM 128
#define HD 96
#define BN_EPS 1e-5f
#define PN_SCALE 20.0f
#define SCAN_NB 196   // ceil(50000/256)
#define NREP 4        // cnt replicas: edge e -> replica e&3 (hist AND fill)

using bf16x8 = __attribute__((ext_vector_type(8))) short;
using f32x4  = __attribute__((ext_vector_type(4))) float;

__device__ __forceinline__ float4 ld4(const float* p) { return *(const float4*)p; }
__device__ __forceinline__ float4 add4(float4 a, float4 b) {
    return make_float4(a.x + b.x, a.y + b.y, a.z + b.z, a.w + b.w);
}

// fp32 -> bf16 round-to-nearest-even (bit trick; no builtin dependency)
__device__ __forceinline__ short bfr(float f) {
    unsigned u = __float_as_uint(f);
    unsigned r = u + 0x7fffu + ((u >> 16) & 1u);
    return (short)(r >> 16);
}
__device__ __forceinline__ bf16x8 cvt8(float4 a, float4 b) {
    bf16x8 r;
    r[0] = bfr(a.x); r[1] = bfr(a.y); r[2] = bfr(a.z); r[3] = bfr(a.w);
    r[4] = bfr(b.x); r[5] = bfr(b.y); r[6] = bfr(b.z); r[7] = bfr(b.w);
    return r;
}

// ---------------- zero stats + replicated CSR counters ----------------
__global__ void zero_kernel(float* stats, int* cnt) {
    int i = blockIdx.x * blockDim.x + threadIdx.x;
    if (i < 1024) stats[i] = 0.0f;
    int j = i - 1024;
    if (j >= 0 && j < NREP * NN) cnt[j] = 0;
}

// ---------------- MFMA GEMM: C[N,96] = act(A[N,K]) @ W[96,K]^T + b ----------
// Round-14 postmortem: with all 782 blocks co-resident, gemm0's 48us ~= one
// block's wall time, and a block's real work is ~5K cycles. The wait is the
// __syncthreads() after W-staging: its implicit vmcnt(0) drains the 4 fused
// hist atomics, which queue behind ~256 serialized RMWs per 64B line
// (16 hits/counter x 16 counters/line). Fix: NREP=4 replicated counters
// (edge e -> replica e&3) cuts per-line contention 4x; the same replica
// assignment is used by fill so counts match. Scan sums replicas.
// MFMA structure unchanged from the passing round-14 kernel.
template<int K, int MODE>
__global__ __launch_bounds__(256) void gemm_mfma(
    const float* A, const float* __restrict__ W, const float* __restrict__ bias,
    float* out, const float* __restrict__ scale, const float* __restrict__ shift,
    float* __restrict__ gsum, float* __restrict__ gsumsq,
    float* __restrict__ gcol, float* __restrict__ growss,
    const int* __restrict__ ei, int* __restrict__ hist_cnt, int E)
{
    constexpr int P     = K + 8;   // bf16 pitch: 16B-aligned rows, spread banks
    constexpr int NS    = K / 32;  // K-steps
    constexpr int KD4   = K / 4;   // dword4 chunks per W row
    constexpr int WITER = (96 * KD4) / 256;   // 12 (K=128) / 9 (K=96)
    constexpr int WL_SH  = 96 * P;            // shorts actually used
    constexpr int WL_TOT = (20608 > WL_SH) ? 20608 : WL_SH;  // 41216 B ->
    __shared__ short Wl[WL_TOT];   // LDS caps occupancy at 3 blocks/CU (= grid)

    const int t    = threadIdx.x;
    const int l    = t & 63;
    const int w    = t >> 6;       // wave 0..3
    const int l15  = l & 15;
    const int lh   = l >> 4;       // 0..3
    const int base = blockIdx.x * 64;

    const int  arow = base + w * 16 + l15;
    const bool aok  = arow < NN;
    const float* Ap = A + (size_t)arow * K + lh * 8;
    const float4 Z4 = make_float4(0.f, 0.f, 0.f, 0.f);

    // ---- cluster ALL global loads up front ----
    float4 pa[2 * NS];
#pragma unroll
    for (int s = 0; s < NS; ++s) {
        pa[2 * s]     = aok ? ld4(Ap + s * 32)     : Z4;
        pa[2 * s + 1] = aok ? ld4(Ap + s * 32 + 4) : Z4;
    }
    float4 wv[WITER];
#pragma unroll
    for (int i = 0; i < WITER; ++i) {
        int c = t + i * 256;
        int row = c / KD4, kq = c - row * KD4;
        wv[i] = ld4(W + (size_t)row * K + kq * 4);
    }
    float4 scv[2 * NS], shv[2 * NS];
    if (MODE == 2) {
#pragma unroll
        for (int s = 0; s < 2 * NS; ++s) {
            scv[s] = ld4(scale + (s >> 1) * 32 + lh * 8 + (s & 1) * 4);
            shv[s] = ld4(shift + (s >> 1) * 32 + lh * 8 + (s & 1) * 4);
        }
    }

    if (MODE == 0) {               // fused histogram: 4 edges/thread, replicated
        int e0 = (blockIdx.x * 256 + t) * 4;   // e0 % 4 == 0 -> replica = i
        if (e0 + 4 <= E) {
            int4 d4 = *(const int4*)(ei + E + e0);
            atomicAdd(&hist_cnt[0 * NN + d4.x], 1);
            atomicAdd(&hist_cnt[1 * NN + d4.y], 1);
            atomicAdd(&hist_cnt[2 * NN + d4.z], 1);
            atomicAdd(&hist_cnt[3 * NN + d4.w], 1);
        } else {
            for (int i = 0; i < 4; ++i) {
                int e = e0 + i;
                if (e < E) atomicAdd(&hist_cnt[(e & 3) * NN + ei[E + e]], 1);
            }
        }
    }

    // ---- convert A early (waits only on A loads; frees 2*NS float4s) ----
    bf16x8 af[NS];
#pragma unroll
    for (int s = 0; s < NS; ++s) {
        float4 q0 = pa[2 * s], q1 = pa[2 * s + 1];
        if (MODE == 2) {
            float4 sc0 = scv[2 * s], sh0 = shv[2 * s];
            float4 sc1 = scv[2 * s + 1], sh1 = shv[2 * s + 1];
            q0.x = fmaxf(q0.x * sc0.x + sh0.x, 0.f);
            q0.y = fmaxf(q0.y * sc0.y + sh0.y, 0.f);
            q0.z = fmaxf(q0.z * sc0.z + sh0.z, 0.f);
            q0.w = fmaxf(q0.w * sc0.w + sh0.w, 0.f);
            q1.x = fmaxf(q1.x * sc1.x + sh1.x, 0.f);
            q1.y = fmaxf(q1.y * sc1.y + sh1.y, 0.f);
            q1.z = fmaxf(q1.z * sc1.z + sh1.z, 0.f);
            q1.w = fmaxf(q1.w * sc1.w + sh1.w, 0.f);
        }
        af[s] = cvt8(q0, q1);
    }

    // ---- convert + stage W -> bf16 LDS ----
#pragma unroll
    for (int i = 0; i < WITER; ++i) {
        int c = t + i * 256;
        int row = c / KD4, kq = c - row * KD4;
        short4 s4v;
        s4v.x = bfr(wv[i].x); s4v.y = bfr(wv[i].y);
        s4v.z = bfr(wv[i].z); s4v.w = bfr(wv[i].w);
        *(short4*)(Wl + row * P + kq * 4) = s4v;
    }
    __syncthreads();

    f32x4 acc[6];
#pragma unroll
    for (int n = 0; n < 6; ++n) acc[n] = (f32x4){0.f, 0.f, 0.f, 0.f};

#pragma unroll
    for (int s = 0; s < NS; ++s) {
        const short* wp = Wl + s * 32 + lh * 8;
#pragma unroll
        for (int n = 0; n < 6; ++n) {
            bf16x8 bf = *(const bf16x8*)(wp + (n * 16 + l15) * P);
            acc[n] = __builtin_amdgcn_mfma_f32_16x16x32_bf16(af[s], bf, acc[n], 0, 0, 0);
        }
    }

    // ---- epilogue: bias + store (C: col=l15, row=lh*4+r within wave tile) ----
    float cv[6][4];
#pragma unroll
    for (int n = 0; n < 6; ++n) {
        float b = bias[n * 16 + l15];
#pragma unroll
        for (int r = 0; r < 4; ++r) cv[n][r] = acc[n][r] + b;
    }
    int crow[4]; bool cok[4];
#pragma unroll
    for (int r = 0; r < 4; ++r) {
        crow[r] = base + w * 16 + lh * 4 + r;
        cok[r]  = crow[r] < NN;
    }
#pragma unroll
    for (int r = 0; r < 4; ++r) {
        if (cok[r]) {
            float* o = out + (size_t)crow[r] * HD + l15;
#pragma unroll
            for (int n = 0; n < 6; ++n) o[n * 16] = cv[n][r];
        }
    }

    if (MODE == 1) {
        float s[6], q[6];
#pragma unroll
        for (int n = 0; n < 6; ++n) {
            s[n] = 0.f; q[n] = 0.f;
#pragma unroll
            for (int r = 0; r < 4; ++r) {
                float v = cok[r] ? cv[n][r] : 0.f;
                s[n] += v; q[n] += v * v;
            }
        }
#pragma unroll
        for (int n = 0; n < 6; ++n) {
            s[n] += __shfl_xor(s[n], 16); s[n] += __shfl_xor(s[n], 32);
            q[n] += __shfl_xor(q[n], 16); q[n] += __shfl_xor(q[n], 32);
        }
        __syncthreads();                       // Wl dead everywhere; overlay
        float* red0 = (float*)Wl;              // [4][96]
        float* red1 = red0 + 384;              // [4][96]
        if (lh == 0) {
#pragma unroll
            for (int n = 0; n < 6; ++n) {
                red0[w * 96 + n * 16 + l15] = s[n];
                red1[w * 96 + n * 16 + l15] = q[n];
            }
        }
        __syncthreads();
        if (t < HD) {
            float S = red0[t] + red0[96 + t] + red0[192 + t] + red0[288 + t];
            float Q = red1[t] + red1[96 + t] + red1[192 + t] + red1[288 + t];
            atomicAdd(&gsum[t], S);
            atomicAdd(&gsumsq[t], Q);
        }
    }

    if (MODE == 2) {
        float s[6];
#pragma unroll
        for (int n = 0; n < 6; ++n) {
            s[n] = 0.f;
#pragma unroll
            for (int r = 0; r < 4; ++r) s[n] += cok[r] ? cv[n][r] : 0.f;
        }
#pragma unroll
        for (int n = 0; n < 6; ++n) {
            s[n] += __shfl_xor(s[n], 16); s[n] += __shfl_xor(s[n], 32);
        }
        float rq[4];
#pragma unroll
        for (int r = 0; r < 4; ++r) {
            float v = 0.f;
#pragma unroll
            for (int n = 0; n < 6; ++n) v = fmaf(cv[n][r], cv[n][r], v);
            v += __shfl_xor(v, 1); v += __shfl_xor(v, 2);
            v += __shfl_xor(v, 4); v += __shfl_xor(v, 8);
            rq[r] = v;
        }
        __syncthreads();                       // Wl dead; overlay
        float* red0 = (float*)Wl;              // [4][96]
        if (lh == 0) {
#pragma unroll
            for (int n = 0; n < 6; ++n) red0[w * 96 + n * 16 + l15] = s[n];
        }
        __syncthreads();
        if (t < HD) {
            float S = red0[t] + red0[96 + t] + red0[192 + t] + red0[288 + t];
            atomicAdd(&gcol[t], S);
        }
        if (l15 == 0) {
#pragma unroll
            for (int r = 0; r < 4; ++r)
                if (cok[r]) growss[crow[r]] = rq[r];
        }
    }
}

// ---------------- CSR build (4-replica counts) ----------------
__global__ __launch_bounds__(256) void scan_part1(const int* __restrict__ cnt,
                                                  int* __restrict__ bsum) {
    __shared__ int sh[256];
    int i = blockIdx.x * 256 + threadIdx.x;
    int t = threadIdx.x;
    int v = 0;
    if (i < NN)
        v = cnt[i] + cnt[NN + i] + cnt[2 * NN + i] + cnt[3 * NN + i];
    sh[t] = v;
    __syncthreads();
    for (int off = 128; off > 0; off >>= 1) {
        if (t < off) sh[t] += sh[t + off];
        __syncthreads();
    }
    if (t == 0) bsum[blockIdx.x] = sh[0];
}

__global__ __launch_bounds__(256) void scan_part2(int* __restrict__ bsum) {
    __shared__ int sh[256];
    int t = threadIdx.x;
    int v = (t < SCAN_NB) ? bsum[t] : 0;
    sh[t] = v;
    __syncthreads();
    for (int off = 1; off < 256; off <<= 1) {
        int u = sh[t];
        if (t >= off) u += sh[t - off];
        __syncthreads();
        sh[t] = u;
        __syncthreads();
    }
    if (t < SCAN_NB) bsum[t] = sh[t] - v;    // exclusive block offsets
}

__global__ __launch_bounds__(256) void scan_part3(int* __restrict__ cnt,
                                                  const int* __restrict__ bsum,
                                                  int* __restrict__ rowptr) {
    __shared__ int sh[256];
    int i = blockIdx.x * 256 + threadIdx.x;
    int t = threadIdx.x;
    int c0 = 0, c1 = 0, c2 = 0, c3 = 0;
    if (i < NN) {
        c0 = cnt[i]; c1 = cnt[NN + i]; c2 = cnt[2 * NN + i]; c3 = cnt[3 * NN + i];
    }
    int v = c0 + c1 + c2 + c3;
    sh[t] = v;
    __syncthreads();
    for (int off = 1; off < 256; off <<= 1) {
        int u = sh[t];
        if (t >= off) u += sh[t - off];
        __syncthreads();
        sh[t] = u;
        __syncthreads();
    }
    int excl = sh[t] - v + bsum[blockIdx.x];
    if (i < NN) {
        rowptr[i] = excl;
        // cnt becomes the 4 sub-cursors: row range [excl, excl+v) split by replica
        cnt[i]          = excl;
        cnt[NN + i]     = excl + c0;
        cnt[2 * NN + i] = excl + c0 + c1;
        cnt[3 * NN + i] = excl + c0 + c1 + c2;
    }
    if (i == NN - 1) rowptr[NN] = excl + v;
}

// fill with dst-range multipass + replicated cursors: edge e -> cursor replica
// e&3 (matches hist), cutting per-line atomic contention 4x (round-14 lesson:
// atomic line-serialization, not load-issue, was the 46us floor). Multipass
// dst-clustering kept (round-1 A/B: removing it cost 20% WRITE + 18% time).
__global__ __launch_bounds__(256) void fill_kernel(const int* __restrict__ ei,
                                                   int* __restrict__ cursor,
                                                   int* __restrict__ srcs, int E) {
    int t2 = blockIdx.x * 256 + threadIdx.x;
    int e0 = t2 * 2;
    int src[2], dst[2], rep[2];
#pragma unroll
    for (int i = 0; i < 2; ++i) {
        int e = e0 + i;
        bool ok = e < E;
        dst[i] = ok ? ei[E + e] : -1;
        src[i] = ok ? ei[e] : 0;
        rep[i] = e & 3;
    }
    for (int pass = 0; pass < 7; ++pass) {
#pragma unroll
        for (int i = 0; i < 2; ++i) {
            if (dst[i] >= 0 && (dst[i] >> 13) == pass) {
                int slot = atomicAdd(&cursor[rep[i] * NN + dst[i]], 1);
                srcs[slot] = src[i];
            }
        }
    }
}

// -------- gather: z[i] = h0[i] + sum_{e:dst=i} h0[src_e] --------------------
// One 24-lane group owns a full row (24 x float4 = 96 floats). No LDS, no
// __syncthreads: waves retire independently, 8-deep load batches give MLP.
__global__ __launch_bounds__(192) void gather_kernel(
    const float* __restrict__ h0, const int* __restrict__ rowptr,
    const int* __restrict__ srcs, float* __restrict__ z)
{
    const int tid = threadIdx.x;
    const int rl  = tid / 24;          // 0..7 local row
    const int c   = tid - rl * 24;     // 0..23 float4 lane
    const int row = blockIdx.x * 8 + rl;
    if (row >= NN) return;

    const int p0 = rowptr[row];
    const int p1 = rowptr[row + 1];

    float4 acc = ld4(h0 + (size_t)row * HD + c * 4);

    int p = p0;
    for (; p + 8 <= p1; p += 8) {
        int s0 = srcs[p + 0], s1 = srcs[p + 1], s2 = srcs[p + 2], s3 = srcs[p + 3];
        int s4 = srcs[p + 4], s5 = srcs[p + 5], s6 = srcs[p + 6], s7 = srcs[p + 7];
        float4 v0 = ld4(h0 + (size_t)s0 * HD + c * 4);
        float4 v1 = ld4(h0 + (size_t)s1 * HD + c * 4);
        float4 v2 = ld4(h0 + (size_t)s2 * HD + c * 4);
        float4 v3 = ld4(h0 + (size_t)s3 * HD + c * 4);
        float4 v4 = ld4(h0 + (size_t)s4 * HD + c * 4);
        float4 v5 = ld4(h0 + (size_t)s5 * HD + c * 4);
        float4 v6 = ld4(h0 + (size_t)s6 * HD + c * 4);
        float4 v7 = ld4(h0 + (size_t)s7 * HD + c * 4);
        acc = add4(acc, add4(add4(add4(v0, v1), add4(v2, v3)),
                             add4(add4(v4, v5), add4(v6, v7))));
    }
    for (; p + 4 <= p1; p += 4) {
        int s0 = srcs[p + 0], s1 = srcs[p + 1], s2 = srcs[p + 2], s3 = srcs[p + 3];
        float4 v0 = ld4(h0 + (size_t)s0 * HD + c * 4);
        float4 v1 = ld4(h0 + (size_t)s1 * HD + c * 4);
        float4 v2 = ld4(h0 + (size_t)s2 * HD + c * 4);
        float4 v3 = ld4(h0 + (size_t)s3 * HD + c * 4);
        acc = add4(acc, add4(add4(v0, v1), add4(v2, v3)));
    }
    for (; p < p1; ++p)
        acc = add4(acc, ld4(h0 + (size_t)srcs[p] * HD + c * 4));

    *(float4*)(z + (size_t)row * HD + c * 4) = acc;
}

__global__ void bn_finalize_kernel(const float* __restrict__ sum, const float* __restrict__ sumsq,
                                   const float* __restrict__ gamma, const float* __restrict__ beta,
                                   float* __restrict__ scale, float* __restrict__ shift)
{
    int f = threadIdx.x;
    if (f < HD) {
        float mean = sum[f] * (1.0f / NN);
        float var  = fmaxf(sumsq[f] * (1.0f / NN) - mean * mean, 0.0f);
        float rstd = rsqrtf(var + BN_EPS);
        float sc = rstd * gamma[f];
        scale[f] = sc;
        shift[f] = beta[f] - mean * sc;
    }
}

// ---------------- PairNorm: streaming float4, in place ----------------
__global__ __launch_bounds__(256) void pn_kernel(float* l1, const float* __restrict__ colsum,
                                                 const float* __restrict__ rowss)
{
    int idx = blockIdx.x * 256 + threadIdx.x;   // float4 index
    if (idx >= NN * 24) return;
    int row = idx / 24;
    int q = idx - row * 24;
    float rs = rsqrtf(1e-6f + rowss[row]);
    float4 v = ld4(l1 + (size_t)idx * 4);
    float4 cm = ld4(colsum + q * 4);
    v.x = PN_SCALE * v.x * rs - cm.x * (1.0f / NN);
    v.y = PN_SCALE * v.y * rs - cm.y * (1.0f / NN);
    v.z = PN_SCALE * v.z * rs - cm.z * (1.0f / NN);
    v.w = PN_SCALE * v.w * rs - cm.w * (1.0f / NN);
    *(float4*)(l1 + (size_t)idx * 4) = v;
}

extern "C" void kernel_launch(void* const* d_in, const int* in_sizes, int n_in,
                              void* d_out, int out_size, void* d_ws, size_t ws_size,
                              hipStream_t stream) {
    const float* x     = (const float*)d_in[0];
    const int*   ei    = (const int*)d_in[1];
    const float* W0    = (const float*)d_in[2];
    const float* b0    = (const float*)d_in[3];
    const float* W1    = (const float*)d_in[4];
    const float* b1    = (const float*)d_in[5];
    const float* gamma = (const float*)d_in[6];
    const float* beta  = (const float*)d_in[7];
    const float* W2    = (const float*)d_in[8];
    const float* b2    = (const float*)d_in[9];

    float* out_l1 = (float*)d_out;                 // [N,96]: z -> h -> l1 (in place)
    float* out_h0 = out_l1 + (size_t)NN * HD;      // [N,96]: h0 output

    float* stats   = (float*)d_ws;
    float* s_sum   = stats;            // 96
    float* s_sumsq = stats + HD;       // 96
    float* s_col   = stats + 2 * HD;   // 96
    float* s_scale = stats + 288;      // 96
    float* s_shift = stats + 384;      // 96
    float* rowss = stats + 1024;
    int* cnt    = (int*)(rowss + NN);              // [NREP][NN] replicated
    int* rowptr = cnt + NREP * NN;
    int* bsum   = rowptr + NN + 2;
    int* srcs   = bsum + 256;

    const int E = in_sizes[1] / 2;                 // 800000
    const int GB = (NN + 63) / 64;                 // 782

    zero_kernel<<<(1024 + NREP * NN + 255) / 256, 256, 0, stream>>>(stats, cnt);
    // 1) h0 = x @ W0^T + b0 (MFMA), replicated edge histogram fused
    gemm_mfma<IN_DIM, 0><<<GB, 256, 0, stream>>>(x, W0, b0, out_h0, nullptr, nullptr,
                                                 nullptr, nullptr, nullptr, nullptr,
                                                 ei, cnt, E);
    // 2) CSR build: replica-summing scan -> multipass fill w/ replica cursors
    scan_part1<<<SCAN_NB, 256, 0, stream>>>(cnt, bsum);
    scan_part2<<<1, 256, 0, stream>>>(bsum);
    scan_part3<<<SCAN_NB, 256, 0, stream>>>(cnt, bsum, rowptr);
    fill_kernel<<<(E / 2 + 255) / 256, 256, 0, stream>>>(ei, cnt, srcs, E);
    // 3) gather: z = h0 + segment_sum(h0[src])
    gather_kernel<<<(NN + 7) / 8, 192, 0, stream>>>(out_h0, rowptr, srcs, out_l1);
    // 4) h = z @ W1^T + b1 (in place, MFMA) + fused BN stats
    gemm_mfma<HD, 1><<<GB, 256, 0, stream>>>(out_l1, W1, b1, out_l1, nullptr, nullptr,
                                             s_sum, s_sumsq, nullptr, nullptr,
                                             nullptr, nullptr, 0);
    bn_finalize_kernel<<<1, 128, 0, stream>>>(s_sum, s_sumsq, gamma, beta, s_scale, s_shift);
    // 5) l1 = relu(bn(h)) @ W2^T + b2 (in place, MFMA) + fused PN stats
    gemm_mfma<HD, 2><<<GB, 256, 0, stream>>>(out_l1, W2, b2, out_l1, s_scale, s_shift,
                                             nullptr, nullptr, s_col, rowss,
                                             nullptr, nullptr, 0);
    // 6) PairNorm finalize (streaming, in place)
    pn_kernel<<<(NN * 24 + 255) / 256, 256, 0, stream>>>(out_l1, s_col, rowss);
}